// Round 1
// baseline (949.246 us; speedup 1.0000x reference)
//
#include <hip/hip_runtime.h>
#include <hip/hip_bf16.h>

// Problem constants
#define B_    4
#define D_    256
#define H_    56
#define W_    56
#define NH_   28
#define NW_   28
#define HEADS 8
#define DPH   32
#define NPOS  784      // 28*28
#define NS    3136     // 56*56

// ws layout (floats)
#define OFF_REC     0u          // [4][512][784]            1,605,632
#define OFF_HPART   1605632u    // [4cs][4b][784][256]      3,211,264
#define OFF_ATTNOUT 0u          // [32][32][3136] aliases rec+hpart (dead)
#define OFF_LOC     4816896u    // [32][784][2]             50,176
#define OFF_SAMP    4867072u    // [32][32][784]            802,816
#define OFF_Q       5669888u    // [32][32][3136]           3,211,264
#define OFF_KT      8881152u    // [32][784][32]            802,816
#define OFF_VT      9683968u    // [32][784][32]            802,816
// total 10,486,784 floats = 41,947,136 bytes

// ---------------------------------------------------------------------------
// 1. 2x2 avg-pool of query and x, concatenated along channels -> rec[4][512][28][28]
__global__ __launch_bounds__(256) void k_pool(const float* __restrict__ q,
                                              const float* __restrict__ x,
                                              float* __restrict__ rec) {
    int idx = blockIdx.x * 256 + threadIdx.x;      // 1,605,632 exact
    int j = idx % NW_;
    int i = (idx / NW_) % NH_;
    int c = (idx / NPOS) % 512;
    int b = idx / (NPOS * 512);
    const float* src = (c < 256) ? q : x;
    int cc = (c < 256) ? c : (c - 256);
    const float* p = src + ((size_t)(b * 256 + cc) * H_ + i * 2) * W_ + j * 2;
    rec[idx] = 0.25f * (p[0] + p[1] + p[W_] + p[W_ + 1]);
}

// ---------------------------------------------------------------------------
// 2. conv5x5 (512 -> 256), pad 2, partial sums over 128-channel chunks.
//    grid (32 otile, 4 csplit, 4 b), block 256.
//    hpart layout: [cs][b][pos][o256]
__global__ __launch_bounds__(256) void k_conv(const float* __restrict__ rec,
                                              const float* __restrict__ w1,
                                              float* __restrict__ hpart) {
    const int ot = blockIdx.x, cs = blockIdx.y, b = blockIdx.z;
    __shared__ __align__(16) float plane[32 * 33];
    const int tid = threadIdx.x;
    for (int i = tid; i < 32 * 33; i += 256) plane[i] = 0.f;

    int qid = tid;
    const bool qv = (qid < 196);
    int qi = qv ? (qid / 7) : 0;
    int qj = qv ? ((qid % 7) * 4) : 0;

    const float* recb = rec + (size_t)(b * 512 + cs * 128) * NPOS;
    const float* w1b  = w1 + (size_t)(ot * 8) * (512 * 25) + (size_t)(cs * 128) * 25;

    float acc[4][8] = {};
    __syncthreads();

    for (int c = 0; c < 128; ++c) {
        // stage one input plane (with zero halo preserved at borders)
        for (int p = tid; p < NPOS; p += 256)
            plane[(p / NW_ + 2) * 33 + (p % NW_ + 2)] = recb[c * NPOS + p];
        __syncthreads();

        #pragma unroll
        for (int ky = 0; ky < 5; ++ky) {
            float vals[9];
            #pragma unroll
            for (int t = 0; t < 9; ++t) vals[t] = plane[(qi + ky) * 33 + qj + t];
            #pragma unroll
            for (int kx = 0; kx < 5; ++kx) {
                #pragma unroll
                for (int oo = 0; oo < 8; ++oo) {
                    // uniform index -> scalar load (no LDS, no VGPR traffic for w)
                    float wv = w1b[oo * (512 * 25) + c * 25 + ky * 5 + kx];
                    #pragma unroll
                    for (int pi = 0; pi < 4; ++pi)
                        acc[pi][oo] = fmaf(vals[kx + pi], wv, acc[pi][oo]);
                }
            }
        }
        __syncthreads();
    }

    if (qv) {
        #pragma unroll
        for (int pi = 0; pi < 4; ++pi) {
            int pos = qi * NW_ + qj + pi;
            float* hp = hpart + ((size_t)((cs * 4 + b) * NPOS + pos)) * 256 + ot * 8;
            *(float4*)&hp[0] = make_float4(acc[pi][0], acc[pi][1], acc[pi][2], acc[pi][3]);
            *(float4*)&hp[4] = make_float4(acc[pi][4], acc[pi][5], acc[pi][6], acc[pi][7]);
        }
    }
}

// ---------------------------------------------------------------------------
// 3. reduce partials + bias + channel-LayerNorm + exact GELU + 1x1(256->16)
//    + tanh + (ref + off) clip -> loc[32][784][2].  grid (784, 4), block 256.
__global__ __launch_bounds__(256) void k_lnoff(const float* __restrict__ hpart,
                                               const float* __restrict__ b1,
                                               const float* __restrict__ g,
                                               const float* __restrict__ bb,
                                               const float* __restrict__ w2,
                                               const float* __restrict__ b2,
                                               const float* __restrict__ ref,
                                               float* __restrict__ loc) {
    const int pos = blockIdx.x, b = blockIdx.y, c = threadIdx.x;
    float v = b1[c];
    #pragma unroll
    for (int cs = 0; cs < 4; ++cs)
        v += hpart[((size_t)((cs * 4 + b) * NPOS + pos)) * 256 + c];

    float s1 = v, s2 = v * v;
    #pragma unroll
    for (int m = 32; m >= 1; m >>= 1) {
        s1 += __shfl_xor(s1, m);
        s2 += __shfl_xor(s2, m);
    }
    __shared__ float r1[4], r2[4];
    const int wv = c >> 6, ln = c & 63;
    if (ln == 0) { r1[wv] = s1; r2[wv] = s2; }
    __syncthreads();
    s1 = r1[0] + r1[1] + r1[2] + r1[3];
    s2 = r2[0] + r2[1] + r2[2] + r2[3];
    const float mu  = s1 * (1.f / 256.f);
    const float var = s2 * (1.f / 256.f) - mu * mu;
    const float rstd = 1.f / sqrtf(var + 1e-5f);
    const float xn = (v - mu) * rstd * g[c] + bb[c];
    const float ge = 0.5f * xn * (1.f + erff(xn * 0.70710678118654752f));

    __shared__ float ro[4][16];
    for (int o = 0; o < 16; ++o) {
        float pv = ge * w2[o * 256 + c];
        #pragma unroll
        for (int m = 32; m >= 1; m >>= 1) pv += __shfl_xor(pv, m);
        if (ln == 0) ro[wv][o] = pv;
    }
    __syncthreads();
    if (c < 16) {
        float off = ro[0][c] + ro[1][c] + ro[2][c] + ro[3][c] + b2[c];
        float t = tanhf(off);
        int hd = c >> 1, comp = c & 1;
        size_t li = ((size_t)((b * 8 + hd) * NPOS + pos)) * 2 + comp;
        float l = ref[li] + t;
        loc[li] = fminf(1.f, fmaxf(-1.f, l));
    }
}

// ---------------------------------------------------------------------------
// 4. bilinear grid_sample, zeros padding -> samp[32][32][784].
__global__ __launch_bounds__(256) void k_gsample(const float* __restrict__ x,
                                                 const float* __restrict__ loc,
                                                 float* __restrict__ samp) {
    int idx = blockIdx.x * 256 + threadIdx.x;      // 25,088 exact
    int pos = idx % NPOS;
    int bh  = idx / NPOS;
    float gx = loc[(size_t)idx * 2 + 0];
    float gy = loc[(size_t)idx * 2 + 1];
    float ix = (gx + 1.f) * 28.f - 0.5f;
    float iy = (gy + 1.f) * 28.f - 0.5f;
    float x0f = floorf(ix), y0f = floorf(iy);
    int x0 = (int)x0f, y0 = (int)y0f;
    float wx = ix - x0f, wy = iy - y0f;

    int xs[2] = { x0, x0 + 1 };
    int ys[2] = { y0, y0 + 1 };
    float wxs[2] = { 1.f - wx, wx };
    float wys[2] = { 1.f - wy, wy };
    int   cidx[4];
    float cw[4];
    #pragma unroll
    for (int a = 0; a < 2; ++a)
        #pragma unroll
        for (int bb2 = 0; bb2 < 2; ++bb2) {
            int yy = ys[a], xx = xs[bb2];
            bool inb = (xx >= 0) && (xx < W_) && (yy >= 0) && (yy < H_);
            int yyc = min(max(yy, 0), H_ - 1), xxc = min(max(xx, 0), W_ - 1);
            cidx[a * 2 + bb2] = yyc * W_ + xxc;
            cw[a * 2 + bb2] = inb ? (wys[a] * wxs[bb2]) : 0.f;
        }

    const float* xb = x + (size_t)bh * DPH * NS;
    #pragma unroll 4
    for (int c = 0; c < DPH; ++c) {
        const float* xc = xb + (size_t)c * NS;
        float v = cw[0] * xc[cidx[0]] + cw[1] * xc[cidx[1]]
                + cw[2] * xc[cidx[2]] + cw[3] * xc[cidx[3]];
        samp[((size_t)bh * DPH + c) * NPOS + pos] = v;
    }
}

// ---------------------------------------------------------------------------
// 5. 256->256 1x1 projection (q-proj: in2 = pos emb; o-proj: in2 = null).
//    grid (13 schunk, 16 otile, 4 b), block 256.
__global__ __launch_bounds__(256) void k_proj256(const float* __restrict__ in1,
                                                 const float* __restrict__ in2,
                                                 const float* __restrict__ w,
                                                 const float* __restrict__ bias,
                                                 float* __restrict__ out) {
    __shared__ __align__(16) float wl[256 * 16];
    const int tid = threadIdx.x, ot = blockIdx.y, b = blockIdx.z;
    for (int i = tid; i < 4096; i += 256) {
        int oo = i >> 8, c = i & 255;
        wl[c * 16 + oo] = w[(ot * 16 + oo) * 256 + c];
    }
    int s = blockIdx.x * 256 + tid;
    const bool sv = (s < NS);
    const int se = sv ? s : (NS - 1);
    const float* p1 = in1 + (size_t)b * 256 * NS + se;
    const float* p2 = in2 ? (in2 + (size_t)b * 256 * NS + se) : nullptr;
    const bool has2 = (in2 != nullptr);

    float acc[16] = {};
    __syncthreads();
    for (int c = 0; c < 256; ++c) {
        float xv = p1[(size_t)c * NS];
        if (has2) xv += p2[(size_t)c * NS];
        #pragma unroll
        for (int og = 0; og < 4; ++og) {
            float4 w4 = *(const float4*)&wl[c * 16 + og * 4];
            acc[og * 4 + 0] = fmaf(xv, w4.x, acc[og * 4 + 0]);
            acc[og * 4 + 1] = fmaf(xv, w4.y, acc[og * 4 + 1]);
            acc[og * 4 + 2] = fmaf(xv, w4.z, acc[og * 4 + 2]);
            acc[og * 4 + 3] = fmaf(xv, w4.w, acc[og * 4 + 3]);
        }
    }
    if (sv) {
        #pragma unroll
        for (int oo = 0; oo < 16; ++oo) {
            int o = ot * 16 + oo;
            out[((size_t)b * 256 + o) * NS + s] = acc[oo] + bias[o];
        }
    }
}

// ---------------------------------------------------------------------------
// 6. k/v 32->32 projections, written transposed: kt/vt[bh][pos][32].
__global__ __launch_bounds__(256) void k_kv(const float* __restrict__ samp,
                                            const float* __restrict__ kw,
                                            const float* __restrict__ kb,
                                            const float* __restrict__ vw,
                                            const float* __restrict__ vb,
                                            float* __restrict__ kt,
                                            float* __restrict__ vt) {
    __shared__ __align__(16) float kl[1024], vl[1024];
    const int tid = threadIdx.x;
    for (int i = tid; i < 1024; i += 256) {
        int o = i >> 5, c = i & 31;
        kl[c * 32 + o] = kw[i];
        vl[c * 32 + o] = vw[i];
    }
    __syncthreads();
    int idx = blockIdx.x * 256 + tid;   // 25,088 exact
    int pos = idx % NPOS;
    int bh  = idx / NPOS;
    const float* sp = samp + (size_t)bh * DPH * NPOS + pos;
    float ak[32] = {}, av[32] = {};
    for (int c = 0; c < 32; ++c) {
        float sv = sp[(size_t)c * NPOS];
        #pragma unroll
        for (int og = 0; og < 8; ++og) {
            float4 k4 = *(const float4*)&kl[c * 32 + og * 4];
            float4 v4 = *(const float4*)&vl[c * 32 + og * 4];
            ak[og * 4 + 0] = fmaf(sv, k4.x, ak[og * 4 + 0]);
            ak[og * 4 + 1] = fmaf(sv, k4.y, ak[og * 4 + 1]);
            ak[og * 4 + 2] = fmaf(sv, k4.z, ak[og * 4 + 2]);
            ak[og * 4 + 3] = fmaf(sv, k4.w, ak[og * 4 + 3]);
            av[og * 4 + 0] = fmaf(sv, v4.x, av[og * 4 + 0]);
            av[og * 4 + 1] = fmaf(sv, v4.y, av[og * 4 + 1]);
            av[og * 4 + 2] = fmaf(sv, v4.z, av[og * 4 + 2]);
            av[og * 4 + 3] = fmaf(sv, v4.w, av[og * 4 + 3]);
        }
    }
    float* kp = kt + (size_t)idx * 32;
    float* vp = vt + (size_t)idx * 32;
    #pragma unroll
    for (int o = 0; o < 32; ++o) {
        kp[o] = ak[o] + kb[o];
        vp[o] = av[o] + vb[o];
    }
}

// ---------------------------------------------------------------------------
// 7. attention: scores = q.k/16, online softmax, PV. one q-row per thread.
//    grid (25 qchunk, 32 bh), block 128. K/V chunks of 112 in LDS.
__global__ __launch_bounds__(128) void k_attn(const float* __restrict__ q,
                                              const float* __restrict__ kt,
                                              const float* __restrict__ vt,
                                              float* __restrict__ out) {
    __shared__ __align__(16) float K[112 * 32];
    __shared__ __align__(16) float V[112 * 32];
    const int tid = threadIdx.x, bh = blockIdx.y;
    const int s = blockIdx.x * 128 + tid;
    const int se = min(s, NS - 1);
    const float* qp = q + (size_t)bh * DPH * NS + se;
    float qr[32];
    #pragma unroll
    for (int c = 0; c < 32; ++c) qr[c] = qp[(size_t)c * NS];

    float m = -1e30f, l = 0.f;
    float acc[32] = {};

    for (int kv0 = 0; kv0 < NPOS; kv0 += 112) {
        __syncthreads();
        const float* kc = kt + ((size_t)bh * NPOS + kv0) * 32;
        const float* vc = vt + ((size_t)bh * NPOS + kv0) * 32;
        for (int i = tid; i < 112 * 32; i += 128) {
            K[i] = kc[i];
            V[i] = vc[i];
        }
        __syncthreads();
        for (int kv = 0; kv < 112; ++kv) {
            float d0 = 0.f, d1 = 0.f, d2 = 0.f, d3 = 0.f;
            #pragma unroll
            for (int cg = 0; cg < 8; ++cg) {
                float4 k4 = *(const float4*)&K[kv * 32 + cg * 4];
                float* dp = (cg & 1) ? ((cg & 2) ? &d3 : &d1) : ((cg & 2) ? &d2 : &d0);
                *dp = fmaf(qr[cg * 4 + 0], k4.x, *dp);
                *dp = fmaf(qr[cg * 4 + 1], k4.y, *dp);
                *dp = fmaf(qr[cg * 4 + 2], k4.z, *dp);
                *dp = fmaf(qr[cg * 4 + 3], k4.w, *dp);
            }
            float sc = ((d0 + d1) + (d2 + d3)) * (1.f / 16.f);
            if (sc > m) {
                float corr = __expf(m - sc);
                l *= corr;
                #pragma unroll
                for (int c = 0; c < 32; ++c) acc[c] *= corr;
                m = sc;
            }
            float p = __expf(sc - m);
            l += p;
            #pragma unroll
            for (int cg = 0; cg < 8; ++cg) {
                float4 v4 = *(const float4*)&V[kv * 32 + cg * 4];
                acc[cg * 4 + 0] = fmaf(p, v4.x, acc[cg * 4 + 0]);
                acc[cg * 4 + 1] = fmaf(p, v4.y, acc[cg * 4 + 1]);
                acc[cg * 4 + 2] = fmaf(p, v4.z, acc[cg * 4 + 2]);
                acc[cg * 4 + 3] = fmaf(p, v4.w, acc[cg * 4 + 3]);
            }
        }
    }
    if (s < NS) {
        float inv = 1.f / l;
        float* op = out + (size_t)bh * DPH * NS + s;
        #pragma unroll
        for (int c = 0; c < 32; ++c) op[(size_t)c * NS] = acc[c] * inv;
    }
}

// ---------------------------------------------------------------------------
extern "C" void kernel_launch(void* const* d_in, const int* in_sizes, int n_in,
                              void* d_out, int out_size, void* d_ws, size_t ws_size,
                              hipStream_t stream) {
    const float* query = (const float*)d_in[0];
    const float* x     = (const float*)d_in[1];
    const float* refp  = (const float*)d_in[2];
    const float* pe    = (const float*)d_in[3];
    const float* w1    = (const float*)d_in[4];
    const float* b1    = (const float*)d_in[5];
    const float* lng   = (const float*)d_in[6];
    const float* lnb   = (const float*)d_in[7];
    const float* w2    = (const float*)d_in[8];
    const float* b2    = (const float*)d_in[9];
    const float* qw    = (const float*)d_in[10];
    const float* qb    = (const float*)d_in[11];
    const float* kw    = (const float*)d_in[12];
    const float* kb    = (const float*)d_in[13];
    const float* vw    = (const float*)d_in[14];
    const float* vb    = (const float*)d_in[15];
    const float* ow    = (const float*)d_in[16];
    const float* ob    = (const float*)d_in[17];

    float* ws  = (float*)d_ws;
    float* out = (float*)d_out;

    float* rec     = ws + OFF_REC;
    float* hpart   = ws + OFF_HPART;
    float* attnout = ws + OFF_ATTNOUT;   // aliases rec+hpart (both dead by then)
    float* loc     = ws + OFF_LOC;
    float* samp    = ws + OFF_SAMP;
    float* qbuf    = ws + OFF_Q;
    float* ktb     = ws + OFF_KT;
    float* vtb     = ws + OFF_VT;

    k_pool<<<6272, 256, 0, stream>>>(query, x, rec);
    k_conv<<<dim3(32, 4, 4), 256, 0, stream>>>(rec, w1, hpart);
    k_lnoff<<<dim3(784, 4), 256, 0, stream>>>(hpart, b1, lng, lnb, w2, b2, refp, loc);
    k_gsample<<<98, 256, 0, stream>>>(x, loc, samp);
    k_proj256<<<dim3(13, 16, 4), 256, 0, stream>>>(query, pe, qw, qb, qbuf);
    k_kv<<<98, 256, 0, stream>>>(samp, kw, kb, vw, vb, ktb, vtb);
    k_attn<<<dim3(25, 32), 128, 0, stream>>>(qbuf, ktb, vtb, attnout);
    k_proj256<<<dim3(13, 16, 4), 256, 0, stream>>>(attnout, nullptr, ow, ob, out);
}

// Round 2
// 634.333 us; speedup vs baseline: 1.4964x; 1.4964x over previous
//
#include <hip/hip_runtime.h>
#include <hip/hip_bf16.h>

// Problem constants
#define B_    4
#define D_    256
#define H_    56
#define W_    56
#define NH_   28
#define NW_   28
#define HEADS 8
#define DPH   32
#define NPOS  784      // 28*28
#define NS    3136     // 56*56

typedef unsigned short ushort_t;
typedef unsigned int uint_t;
typedef __attribute__((ext_vector_type(8))) short bf16x8;
typedef __attribute__((ext_vector_type(4))) float f32x4;

// ws layout (float offsets)
#define OFF_REC     0u          // [4][512][784]            1,605,632
#define OFF_HPART   1605632u    // [4cs][4b][784][256]      3,211,264
#define OFF_ATTNOUT 0u          // [32][32][3136] aliases rec+hpart (dead by then)
#define OFF_LOC     4816896u    // [32][784][2]             50,176
#define OFF_SAMP    4867072u    // [32][32][784]            802,816
#define OFF_Q       5669888u    // [32][32][3136]           3,211,264
#define OFF_KT      8881152u    // [32][784][32]            802,816
#define OFF_VT      9683968u    // [32][784][32]            802,816
// wrep (ushort arrays) aliased onto SAMP/Q region: only live during conv,
// which runs BEFORE gsample/proj/kv write there.
#define OFF_WREP    4867072u    // wrep_hi: 3,276,800 us ; wrep_lo follows
// total 10,486,784 floats = 41,947,136 bytes

__device__ __forceinline__ ushort_t bf16rne(float f) {
    uint_t u = __float_as_uint(f);
    return (ushort_t)((u + 0x7FFFu + ((u >> 16) & 1u)) >> 16);
}
__device__ __forceinline__ float ubf(ushort_t h) {
    return __uint_as_float(((uint_t)h) << 16);
}

// ---------------------------------------------------------------------------
// 1. 2x2 avg-pool of query and x, concatenated -> rec[4][512][28][28]
__global__ __launch_bounds__(256) void k_pool(const float* __restrict__ q,
                                              const float* __restrict__ x,
                                              float* __restrict__ rec) {
    int idx = blockIdx.x * 256 + threadIdx.x;      // 1,605,632 exact
    int j = idx % NW_;
    int i = (idx / NW_) % NH_;
    int c = (idx / NPOS) % 512;
    int b = idx / (NPOS * 512);
    const float* src = (c < 256) ? q : x;
    int cc = (c < 256) ? c : (c - 256);
    const float* p = src + ((size_t)(b * 256 + cc) * H_ + i * 2) * W_ + j * 2;
    rec[idx] = 0.25f * (p[0] + p[1] + p[W_] + p[W_ + 1]);
}

// ---------------------------------------------------------------------------
// 1b. repack conv weights -> wrep_hi/lo[tap][oc][c] bf16 split (B^T layout:
//     fragment reads 8 contiguous c for a fixed oc).
__global__ __launch_bounds__(256) void k_wrepack(const float* __restrict__ w1,
                                                 ushort_t* __restrict__ wh,
                                                 ushort_t* __restrict__ wl) {
    int idx = blockIdx.x * 256 + threadIdx.x;  // 131072 = oc*512 + c
    const float* wp = w1 + (size_t)idx * 25;
    int oc = idx >> 9, c = idx & 511;
    #pragma unroll 5
    for (int tap = 0; tap < 25; ++tap) {
        float v = wp[tap];
        ushort_t h = bf16rne(v);
        ushort_t l = bf16rne(v - ubf(h));
        size_t o = ((size_t)tap * 256 + oc) * 512 + c;
        wh[o] = h;
        wl[o] = l;
    }
}

// ---------------------------------------------------------------------------
// 2. conv5x5 (512->256) as 25 shifted MFMA GEMMs, bf16 2-way split (3 MFMA
//    per fragment pair => ~fp32 precision). grid (7 mt, 2nt*4cs, 4 b),
//    256 thr = 4 waves (2M x 2N). Each block: M=128 flat positions (padded),
//    N=128 out-chans, K=128 in-chans (4 chunks of 32).
//    Partial sums -> hpart[cs][b][pos][oc] (same layout as before).
__global__ __launch_bounds__(256) void k_conv_mfma(const float* __restrict__ rec,
                                                   const ushort_t* __restrict__ wrep_hi,
                                                   const ushort_t* __restrict__ wrep_lo,
                                                   float* __restrict__ hpart) {
    const int mt = blockIdx.x;                // 0..6
    const int nt = blockIdx.y & 1;            // 0..1
    const int cs = blockIdx.y >> 1;           // 0..3
    const int b  = blockIdx.z;                // 0..3

    const int tid  = threadIdx.x;
    const int lane = tid & 63;
    const int wid  = tid >> 6;
    const int wm = wid & 1, wn = wid >> 1;    // 2M x 2N wave grid
    const int m_in = lane & 15, g = lane >> 4;

    const int p0  = mt * 128;
    const int ylo = p0 / 28;

    // sA: [0..10239] = hi [320 plin][32 c], [10240..20479] = lo
    __shared__ __align__(16) ushort_t sA[20480];

    // per-lane A plin bases for the 4 M-fragments
    int plinb[4];
    #pragma unroll
    for (int mf = 0; mf < 4; ++mf) {
        int p = p0 + wm * 64 + mf * 16 + m_in;   // may be >=784 (pad region)
        int y = p / 28, xx = p - y * 28;
        plinb[mf] = (y - ylo) * 32 + xx;
    }

    // per-lane B base pointers (hi; lo at +3,276,800 elements)
    const int oc0 = nt * 128 + wn * 64;
    const ushort_t* bp[4];
    #pragma unroll
    for (int nf = 0; nf < 4; ++nf) {
        int oc = oc0 + nf * 16 + m_in;
        bp[nf] = wrep_hi + ((size_t)oc << 9) + (g << 3);
    }

    f32x4 acc[4][4];
    #pragma unroll
    for (int i = 0; i < 4; ++i)
        #pragma unroll
        for (int j = 0; j < 4; ++j)
            acc[i][j] = (f32x4){0.f, 0.f, 0.f, 0.f};

#define LOADB(BH, BL, TAP, CB) do {                                          \
    size_t tof_ = (size_t)(TAP) * 131072 + (CB);                             \
    _Pragma("unroll")                                                        \
    for (int nf_ = 0; nf_ < 4; ++nf_) {                                      \
        BH[nf_] = *(const bf16x8*)(bp[nf_] + tof_);                          \
        BL[nf_] = *(const bf16x8*)(bp[nf_] + tof_ + 3276800u);               \
    } } while (0)

#define TAPBODY(BH, BL, TOFF) do {                                           \
    int to_ = (TOFF);                                                        \
    _Pragma("unroll")                                                        \
    for (int mf_ = 0; mf_ < 4; ++mf_) {                                      \
        const int ao_ = ((plinb[mf_] + to_) << 5) + (g << 3);                \
        bf16x8 ah_ = *(const bf16x8*)(sA + ao_);                             \
        bf16x8 al_ = *(const bf16x8*)(sA + 10240 + ao_);                     \
        _Pragma("unroll")                                                    \
        for (int nf_ = 0; nf_ < 4; ++nf_) {                                  \
            acc[mf_][nf_] = __builtin_amdgcn_mfma_f32_16x16x32_bf16(         \
                ah_, BH[nf_], acc[mf_][nf_], 0, 0, 0);                       \
            acc[mf_][nf_] = __builtin_amdgcn_mfma_f32_16x16x32_bf16(         \
                ah_, BL[nf_], acc[mf_][nf_], 0, 0, 0);                       \
            acc[mf_][nf_] = __builtin_amdgcn_mfma_f32_16x16x32_bf16(         \
                al_, BH[nf_], acc[mf_][nf_], 0, 0, 0);                       \
        } } } while (0)

    for (int ch = 0; ch < 4; ++ch) {
        const int cb = cs * 128 + ch * 32;

        // ---- stage A tile: 10 rows x 32 x x 32 c, hi+lo, linear ds_writes
        __syncthreads();
        #pragma unroll
        for (int it = 0; it < 5; ++it) {
            int v  = tid + it * 256;          // 0..1279
            int cg = v & 3, pl = v >> 2;      // pl 0..319
            int ty = pl >> 5, tx = pl & 31;
            int yi = ylo - 2 + ty, xi = tx - 2;
            bool ok = (yi >= 0) && (yi < 28) && (xi >= 0) && (xi < 28);
            const float* rp = rec + ((size_t)(b * 512 + cb + cg * 8)) * NPOS
                              + yi * 28 + xi;
            uint_t hp[4], lp[4];
            #pragma unroll
            for (int i = 0; i < 4; ++i) {
                float v0 = ok ? rp[(size_t)(2 * i) * NPOS] : 0.f;
                float v1 = ok ? rp[(size_t)(2 * i + 1) * NPOS] : 0.f;
                ushort_t h0 = bf16rne(v0);
                ushort_t l0 = bf16rne(v0 - ubf(h0));
                ushort_t h1 = bf16rne(v1);
                ushort_t l1 = bf16rne(v1 - ubf(h1));
                hp[i] = (uint_t)h0 | ((uint_t)h1 << 16);
                lp[i] = (uint_t)l0 | ((uint_t)l1 << 16);
            }
            uint4 hv = make_uint4(hp[0], hp[1], hp[2], hp[3]);
            uint4 lv = make_uint4(lp[0], lp[1], lp[2], lp[3]);
            *(uint4*)(sA + pl * 32 + cg * 8) = hv;
            *(uint4*)(sA + 10240 + pl * 32 + cg * 8) = lv;
        }
        __syncthreads();

        // ---- 25 taps, ping-pong B prefetch
        bf16x8 bh0[4], bl0[4], bh1[4], bl1[4];
        LOADB(bh0, bl0, 0, cb);
        for (int t = 0; t < 24; t += 2) {
            int t1 = t + 1, t2 = (t + 2 <= 24) ? t + 2 : 24;
            LOADB(bh1, bl1, t1, cb);
            TAPBODY(bh0, bl0, (t / 5) * 32 + (t % 5));
            LOADB(bh0, bl0, t2, cb);
            TAPBODY(bh1, bl1, (t1 / 5) * 32 + (t1 % 5));
        }
        TAPBODY(bh0, bl0, 4 * 32 + 4);   // tap 24 = (ky4,kx4)
    }

    // ---- store partials: D row = 4*(lane>>4)+reg, col = lane&15
    #pragma unroll
    for (int mf = 0; mf < 4; ++mf) {
        int prow = p0 + wm * 64 + mf * 16 + g * 4;
        #pragma unroll
        for (int nf = 0; nf < 4; ++nf) {
            int oc = oc0 + nf * 16 + m_in;
            #pragma unroll
            for (int r = 0; r < 4; ++r) {
                int pos = prow + r;
                if (pos < NPOS)
                    hpart[(((size_t)(cs * 4 + b) * NPOS + pos) << 8) + oc] =
                        acc[mf][nf][r];
            }
        }
    }
#undef LOADB
#undef TAPBODY
}

// ---------------------------------------------------------------------------
// 3. reduce partials + bias + channel-LayerNorm + exact GELU + 1x1(256->16)
//    + tanh + (ref + off) clip -> loc[32][784][2].  grid (784, 4), block 256.
__global__ __launch_bounds__(256) void k_lnoff(const float* __restrict__ hpart,
                                               const float* __restrict__ b1,
                                               const float* __restrict__ g,
                                               const float* __restrict__ bb,
                                               const float* __restrict__ w2,
                                               const float* __restrict__ b2,
                                               const float* __restrict__ ref,
                                               float* __restrict__ loc) {
    const int pos = blockIdx.x, b = blockIdx.y, c = threadIdx.x;
    float v = b1[c];
    #pragma unroll
    for (int cs = 0; cs < 4; ++cs)
        v += hpart[((size_t)((cs * 4 + b) * NPOS + pos)) * 256 + c];

    float s1 = v, s2 = v * v;
    #pragma unroll
    for (int m = 32; m >= 1; m >>= 1) {
        s1 += __shfl_xor(s1, m);
        s2 += __shfl_xor(s2, m);
    }
    __shared__ float r1[4], r2[4];
    const int wv = c >> 6, ln = c & 63;
    if (ln == 0) { r1[wv] = s1; r2[wv] = s2; }
    __syncthreads();
    s1 = r1[0] + r1[1] + r1[2] + r1[3];
    s2 = r2[0] + r2[1] + r2[2] + r2[3];
    const float mu  = s1 * (1.f / 256.f);
    const float var = s2 * (1.f / 256.f) - mu * mu;
    const float rstd = 1.f / sqrtf(var + 1e-5f);
    const float xn = (v - mu) * rstd * g[c] + bb[c];
    const float ge = 0.5f * xn * (1.f + erff(xn * 0.70710678118654752f));

    __shared__ float ro[4][16];
    for (int o = 0; o < 16; ++o) {
        float pv = ge * w2[o * 256 + c];
        #pragma unroll
        for (int m = 32; m >= 1; m >>= 1) pv += __shfl_xor(pv, m);
        if (ln == 0) ro[wv][o] = pv;
    }
    __syncthreads();
    if (c < 16) {
        float off = ro[0][c] + ro[1][c] + ro[2][c] + ro[3][c] + b2[c];
        float t = tanhf(off);
        int hd = c >> 1, comp = c & 1;
        size_t li = ((size_t)((b * 8 + hd) * NPOS + pos)) * 2 + comp;
        float l = ref[li] + t;
        loc[li] = fminf(1.f, fmaxf(-1.f, l));
    }
}

// ---------------------------------------------------------------------------
// 4. bilinear grid_sample, zeros padding -> samp[32][32][784].
__global__ __launch_bounds__(256) void k_gsample(const float* __restrict__ x,
                                                 const float* __restrict__ loc,
                                                 float* __restrict__ samp) {
    int idx = blockIdx.x * 256 + threadIdx.x;      // 25,088 exact
    int pos = idx % NPOS;
    int bh  = idx / NPOS;
    float gx = loc[(size_t)idx * 2 + 0];
    float gy = loc[(size_t)idx * 2 + 1];
    float ix = (gx + 1.f) * 28.f - 0.5f;
    float iy = (gy + 1.f) * 28.f - 0.5f;
    float x0f = floorf(ix), y0f = floorf(iy);
    int x0 = (int)x0f, y0 = (int)y0f;
    float wx = ix - x0f, wy = iy - y0f;

    int xs[2] = { x0, x0 + 1 };
    int ys[2] = { y0, y0 + 1 };
    float wxs[2] = { 1.f - wx, wx };
    float wys[2] = { 1.f - wy, wy };
    int   cidx[4];
    float cw[4];
    #pragma unroll
    for (int a = 0; a < 2; ++a)
        #pragma unroll
        for (int bb2 = 0; bb2 < 2; ++bb2) {
            int yy = ys[a], xx = xs[bb2];
            bool inb = (xx >= 0) && (xx < W_) && (yy >= 0) && (yy < H_);
            int yyc = min(max(yy, 0), H_ - 1), xxc = min(max(xx, 0), W_ - 1);
            cidx[a * 2 + bb2] = yyc * W_ + xxc;
            cw[a * 2 + bb2] = inb ? (wys[a] * wxs[bb2]) : 0.f;
        }

    const float* xb = x + (size_t)bh * DPH * NS;
    #pragma unroll 4
    for (int c = 0; c < DPH; ++c) {
        const float* xc = xb + (size_t)c * NS;
        float v = cw[0] * xc[cidx[0]] + cw[1] * xc[cidx[1]]
                + cw[2] * xc[cidx[2]] + cw[3] * xc[cidx[3]];
        samp[((size_t)bh * DPH + c) * NPOS + pos] = v;
    }
}

// ---------------------------------------------------------------------------
// 5. 256->256 1x1 projection (q-proj: in2 = pos emb; o-proj: in2 = null).
__global__ __launch_bounds__(256) void k_proj256(const float* __restrict__ in1,
                                                 const float* __restrict__ in2,
                                                 const float* __restrict__ w,
                                                 const float* __restrict__ bias,
                                                 float* __restrict__ out) {
    __shared__ __align__(16) float wl[256 * 16];
    const int tid = threadIdx.x, ot = blockIdx.y, b = blockIdx.z;
    for (int i = tid; i < 4096; i += 256) {
        int oo = i >> 8, c = i & 255;
        wl[c * 16 + oo] = w[(ot * 16 + oo) * 256 + c];
    }
    int s = blockIdx.x * 256 + tid;
    const bool sv = (s < NS);
    const int se = sv ? s : (NS - 1);
    const float* p1 = in1 + (size_t)b * 256 * NS + se;
    const float* p2 = in2 ? (in2 + (size_t)b * 256 * NS + se) : nullptr;
    const bool has2 = (in2 != nullptr);

    float acc[16] = {};
    __syncthreads();
    for (int c = 0; c < 256; ++c) {
        float xv = p1[(size_t)c * NS];
        if (has2) xv += p2[(size_t)c * NS];
        #pragma unroll
        for (int og = 0; og < 4; ++og) {
            float4 w4 = *(const float4*)&wl[c * 16 + og * 4];
            acc[og * 4 + 0] = fmaf(xv, w4.x, acc[og * 4 + 0]);
            acc[og * 4 + 1] = fmaf(xv, w4.y, acc[og * 4 + 1]);
            acc[og * 4 + 2] = fmaf(xv, w4.z, acc[og * 4 + 2]);
            acc[og * 4 + 3] = fmaf(xv, w4.w, acc[og * 4 + 3]);
        }
    }
    if (sv) {
        #pragma unroll
        for (int oo = 0; oo < 16; ++oo) {
            int o = ot * 16 + oo;
            out[((size_t)b * 256 + o) * NS + s] = acc[oo] + bias[o];
        }
    }
}

// ---------------------------------------------------------------------------
// 6. k/v 32->32 projections, written transposed: kt/vt[bh][pos][32].
__global__ __launch_bounds__(256) void k_kv(const float* __restrict__ samp,
                                            const float* __restrict__ kw,
                                            const float* __restrict__ kb,
                                            const float* __restrict__ vw,
                                            const float* __restrict__ vb,
                                            float* __restrict__ kt,
                                            float* __restrict__ vt) {
    __shared__ __align__(16) float kl[1024], vl[1024];
    const int tid = threadIdx.x;
    for (int i = tid; i < 1024; i += 256) {
        int o = i >> 5, c = i & 31;
        kl[c * 32 + o] = kw[i];
        vl[c * 32 + o] = vw[i];
    }
    __syncthreads();
    int idx = blockIdx.x * 256 + tid;   // 25,088 exact
    int pos = idx % NPOS;
    int bh  = idx / NPOS;
    const float* sp = samp + (size_t)bh * DPH * NPOS + pos;
    float ak[32] = {}, av[32] = {};
    for (int c = 0; c < 32; ++c) {
        float sv = sp[(size_t)c * NPOS];
        #pragma unroll
        for (int og = 0; og < 8; ++og) {
            float4 k4 = *(const float4*)&kl[c * 32 + og * 4];
            float4 v4 = *(const float4*)&vl[c * 32 + og * 4];
            ak[og * 4 + 0] = fmaf(sv, k4.x, ak[og * 4 + 0]);
            ak[og * 4 + 1] = fmaf(sv, k4.y, ak[og * 4 + 1]);
            ak[og * 4 + 2] = fmaf(sv, k4.z, ak[og * 4 + 2]);
            ak[og * 4 + 3] = fmaf(sv, k4.w, ak[og * 4 + 3]);
            av[og * 4 + 0] = fmaf(sv, v4.x, av[og * 4 + 0]);
            av[og * 4 + 1] = fmaf(sv, v4.y, av[og * 4 + 1]);
            av[og * 4 + 2] = fmaf(sv, v4.z, av[og * 4 + 2]);
            av[og * 4 + 3] = fmaf(sv, v4.w, av[og * 4 + 3]);
        }
    }
    float* kp = kt + (size_t)idx * 32;
    float* vp = vt + (size_t)idx * 32;
    #pragma unroll
    for (int o = 0; o < 32; ++o) {
        kp[o] = ak[o] + kb[o];
        vp[o] = av[o] + vb[o];
    }
}

// ---------------------------------------------------------------------------
// 7. attention: scores = q.k/16, online softmax, PV. one q-row per thread.
__global__ __launch_bounds__(128) void k_attn(const float* __restrict__ q,
                                              const float* __restrict__ kt,
                                              const float* __restrict__ vt,
                                              float* __restrict__ out) {
    __shared__ __align__(16) float K[112 * 32];
    __shared__ __align__(16) float V[112 * 32];
    const int tid = threadIdx.x, bh = blockIdx.y;
    const int s = blockIdx.x * 128 + tid;
    const int se = min(s, NS - 1);
    const float* qp = q + (size_t)bh * DPH * NS + se;
    float qr[32];
    #pragma unroll
    for (int c = 0; c < 32; ++c) qr[c] = qp[(size_t)c * NS];

    float m = -1e30f, l = 0.f;
    float acc[32] = {};

    for (int kv0 = 0; kv0 < NPOS; kv0 += 112) {
        __syncthreads();
        const float* kc = kt + ((size_t)bh * NPOS + kv0) * 32;
        const float* vc = vt + ((size_t)bh * NPOS + kv0) * 32;
        for (int i = tid; i < 112 * 32; i += 128) {
            K[i] = kc[i];
            V[i] = vc[i];
        }
        __syncthreads();
        for (int kv = 0; kv < 112; ++kv) {
            float d0 = 0.f, d1 = 0.f, d2 = 0.f, d3 = 0.f;
            #pragma unroll
            for (int cg = 0; cg < 8; ++cg) {
                float4 k4 = *(const float4*)&K[kv * 32 + cg * 4];
                float* dp = (cg & 1) ? ((cg & 2) ? &d3 : &d1) : ((cg & 2) ? &d2 : &d0);
                *dp = fmaf(qr[cg * 4 + 0], k4.x, *dp);
                *dp = fmaf(qr[cg * 4 + 1], k4.y, *dp);
                *dp = fmaf(qr[cg * 4 + 2], k4.z, *dp);
                *dp = fmaf(qr[cg * 4 + 3], k4.w, *dp);
            }
            float sc = ((d0 + d1) + (d2 + d3)) * (1.f / 16.f);
            if (sc > m) {
                float corr = __expf(m - sc);
                l *= corr;
                #pragma unroll
                for (int c = 0; c < 32; ++c) acc[c] *= corr;
                m = sc;
            }
            float p = __expf(sc - m);
            l += p;
            #pragma unroll
            for (int cg = 0; cg < 8; ++cg) {
                float4 v4 = *(const float4*)&V[kv * 32 + cg * 4];
                acc[cg * 4 + 0] = fmaf(p, v4.x, acc[cg * 4 + 0]);
                acc[cg * 4 + 1] = fmaf(p, v4.y, acc[cg * 4 + 1]);
                acc[cg * 4 + 2] = fmaf(p, v4.z, acc[cg * 4 + 2]);
                acc[cg * 4 + 3] = fmaf(p, v4.w, acc[cg * 4 + 3]);
            }
        }
    }
    if (s < NS) {
        float inv = 1.f / l;
        float* op = out + (size_t)bh * DPH * NS + s;
        #pragma unroll
        for (int c = 0; c < 32; ++c) op[(size_t)c * NS] = acc[c] * inv;
    }
}

// ---------------------------------------------------------------------------
extern "C" void kernel_launch(void* const* d_in, const int* in_sizes, int n_in,
                              void* d_out, int out_size, void* d_ws, size_t ws_size,
                              hipStream_t stream) {
    const float* query = (const float*)d_in[0];
    const float* x     = (const float*)d_in[1];
    const float* refp  = (const float*)d_in[2];
    const float* pe    = (const float*)d_in[3];
    const float* w1    = (const float*)d_in[4];
    const float* b1    = (const float*)d_in[5];
    const float* lng   = (const float*)d_in[6];
    const float* lnb   = (const float*)d_in[7];
    const float* w2    = (const float*)d_in[8];
    const float* b2    = (const float*)d_in[9];
    const float* qw    = (const float*)d_in[10];
    const float* qb    = (const float*)d_in[11];
    const float* kw    = (const float*)d_in[12];
    const float* kb    = (const float*)d_in[13];
    const float* vw    = (const float*)d_in[14];
    const float* vb    = (const float*)d_in[15];
    const float* ow    = (const float*)d_in[16];
    const float* ob    = (const float*)d_in[17];

    float* ws  = (float*)d_ws;
    float* out = (float*)d_out;

    float* rec     = ws + OFF_REC;
    float* hpart   = ws + OFF_HPART;
    float* attnout = ws + OFF_ATTNOUT;   // aliases rec+hpart (both dead by then)
    float* loc     = ws + OFF_LOC;
    float* samp    = ws + OFF_SAMP;
    float* qbuf    = ws + OFF_Q;
    float* ktb     = ws + OFF_KT;
    float* vtb     = ws + OFF_VT;
    ushort_t* wrep_hi = (ushort_t*)(ws + OFF_WREP);      // 3,276,800 ushorts
    ushort_t* wrep_lo = wrep_hi + 3276800u;              // ditto (dead after conv)

    k_pool<<<6272, 256, 0, stream>>>(query, x, rec);
    k_wrepack<<<512, 256, 0, stream>>>(w1, wrep_hi, wrep_lo);
    k_conv_mfma<<<dim3(7, 8, 4), 256, 0, stream>>>(rec, wrep_hi, wrep_lo, hpart);
    k_lnoff<<<dim3(784, 4), 256, 0, stream>>>(hpart, b1, lng, lnb, w2, b2, refp, loc);
    k_gsample<<<98, 256, 0, stream>>>(x, loc, samp);
    k_proj256<<<dim3(13, 16, 4), 256, 0, stream>>>(query, pe, qw, qb, qbuf);
    k_kv<<<98, 256, 0, stream>>>(samp, kw, kb, vw, vb, ktb, vtb);
    k_attn<<<dim3(25, 32), 128, 0, stream>>>(qbuf, ktb, vtb, attnout);
    k_proj256<<<dim3(13, 16, 4), 256, 0, stream>>>(attnout, nullptr, ow, ob, out);
}

// Round 3
// 363.462 us; speedup vs baseline: 2.6117x; 1.7453x over previous
//
#include <hip/hip_runtime.h>
#include <hip/hip_bf16.h>

// Problem constants
#define B_    4
#define D_    256
#define H_    56
#define W_    56
#define NH_   28
#define NW_   28
#define HEADS 8
#define DPH   32
#define NPOS  784      // 28*28
#define NS    3136     // 56*56

typedef unsigned short ushort_t;
typedef unsigned int uint_t;
typedef __attribute__((ext_vector_type(8))) short bf16x8;
typedef __attribute__((ext_vector_type(4))) float f32x4;

// ws layout (float offsets)
#define OFF_REC     0u          // [4][512][784]            1,605,632
#define OFF_HPART   1605632u    // [4cs][4b][784][256]      3,211,264
#define OFF_ATTNOUT 0u          // [4][256][3136] aliases rec+hpart (dead by then)
#define OFF_LOC     4816896u    // [32][784][2]             50,176
#define OFF_SAMP    4867072u    // [32][32][784]            802,816
#define OFF_Q       5669888u    // [4][256][3136] fp32      3,211,264 (ends 8,881,152)
#define OFF_KTB     8881152u    // bf16 [32][784][32]       802,816 us = 401,408 f
#define OFF_VTB     9282560u    // bf16 [32][32][784]+pad   802,944 us = 401,472 f
// wrep (ushort arrays) aliased onto SAMP+QBUF region: only live during conv,
// which runs BEFORE gsample/proj/kv write there.
#define OFF_WREP    4867072u    // wrep_hi: 3,276,800 us ; wrep_lo follows
// total 9,684,032 floats = 38.7 MB

__device__ __forceinline__ ushort_t bf16rne(float f) {
    uint_t u = __float_as_uint(f);
    return (ushort_t)((u + 0x7FFFu + ((u >> 16) & 1u)) >> 16);
}
__device__ __forceinline__ float ubf(ushort_t h) {
    return __uint_as_float(((uint_t)h) << 16);
}
__device__ __forceinline__ uint_t cvtpk_bf16(float a, float b) {
    uint_t r;
    asm("v_cvt_pk_bf16_f32 %0, %1, %2" : "=v"(r) : "v"(a), "v"(b));
    return r;
}

// ---------------------------------------------------------------------------
// 1. 2x2 avg-pool of query and x, concatenated -> rec[4][512][28][28]
__global__ __launch_bounds__(256) void k_pool(const float* __restrict__ q,
                                              const float* __restrict__ x,
                                              float* __restrict__ rec) {
    int idx = blockIdx.x * 256 + threadIdx.x;      // 1,605,632 exact
    int j = idx % NW_;
    int i = (idx / NW_) % NH_;
    int c = (idx / NPOS) % 512;
    int b = idx / (NPOS * 512);
    const float* src = (c < 256) ? q : x;
    int cc = (c < 256) ? c : (c - 256);
    const float* p = src + ((size_t)(b * 256 + cc) * H_ + i * 2) * W_ + j * 2;
    rec[idx] = 0.25f * (p[0] + p[1] + p[W_] + p[W_ + 1]);
}

// ---------------------------------------------------------------------------
// 1b. repack conv weights -> wrep_hi/lo[tap][oc][c] bf16 split.
__global__ __launch_bounds__(256) void k_wrepack(const float* __restrict__ w1,
                                                 ushort_t* __restrict__ wh,
                                                 ushort_t* __restrict__ wl) {
    int idx = blockIdx.x * 256 + threadIdx.x;  // 131072 = oc*512 + c
    const float* wp = w1 + (size_t)idx * 25;
    int oc = idx >> 9, c = idx & 511;
    #pragma unroll 5
    for (int tap = 0; tap < 25; ++tap) {
        float v = wp[tap];
        ushort_t h = bf16rne(v);
        ushort_t l = bf16rne(v - ubf(h));
        size_t o = ((size_t)tap * 256 + oc) * 512 + c;
        wh[o] = h;
        wl[o] = l;
    }
}

// ---------------------------------------------------------------------------
// 2. conv5x5 (512->256) as 25 shifted MFMA GEMMs, bf16 2-way split.
__global__ __launch_bounds__(256) void k_conv_mfma(const float* __restrict__ rec,
                                                   const ushort_t* __restrict__ wrep_hi,
                                                   const ushort_t* __restrict__ wrep_lo,
                                                   float* __restrict__ hpart) {
    const int mt = blockIdx.x;                // 0..6
    const int nt = blockIdx.y & 1;            // 0..1
    const int cs = blockIdx.y >> 1;           // 0..3
    const int b  = blockIdx.z;                // 0..3

    const int tid  = threadIdx.x;
    const int lane = tid & 63;
    const int wid  = tid >> 6;
    const int wm = wid & 1, wn = wid >> 1;    // 2M x 2N wave grid
    const int m_in = lane & 15, g = lane >> 4;

    const int p0  = mt * 128;
    const int ylo = p0 / 28;

    __shared__ __align__(16) ushort_t sA[20480];

    int plinb[4];
    #pragma unroll
    for (int mf = 0; mf < 4; ++mf) {
        int p = p0 + wm * 64 + mf * 16 + m_in;
        int y = p / 28, xx = p - y * 28;
        plinb[mf] = (y - ylo) * 32 + xx;
    }

    const int oc0 = nt * 128 + wn * 64;
    const ushort_t* bp[4];
    #pragma unroll
    for (int nf = 0; nf < 4; ++nf) {
        int oc = oc0 + nf * 16 + m_in;
        bp[nf] = wrep_hi + ((size_t)oc << 9) + (g << 3);
    }

    f32x4 acc[4][4];
    #pragma unroll
    for (int i = 0; i < 4; ++i)
        #pragma unroll
        for (int j = 0; j < 4; ++j)
            acc[i][j] = (f32x4){0.f, 0.f, 0.f, 0.f};

#define LOADB(BH, BL, TAP, CB) do {                                          \
    size_t tof_ = (size_t)(TAP) * 131072 + (CB);                             \
    _Pragma("unroll")                                                        \
    for (int nf_ = 0; nf_ < 4; ++nf_) {                                      \
        BH[nf_] = *(const bf16x8*)(bp[nf_] + tof_);                          \
        BL[nf_] = *(const bf16x8*)(bp[nf_] + tof_ + 3276800u);               \
    } } while (0)

#define TAPBODY(BH, BL, TOFF) do {                                           \
    int to_ = (TOFF);                                                        \
    _Pragma("unroll")                                                        \
    for (int mf_ = 0; mf_ < 4; ++mf_) {                                      \
        const int ao_ = ((plinb[mf_] + to_) << 5) + (g << 3);                \
        bf16x8 ah_ = *(const bf16x8*)(sA + ao_);                             \
        bf16x8 al_ = *(const bf16x8*)(sA + 10240 + ao_);                     \
        _Pragma("unroll")                                                    \
        for (int nf_ = 0; nf_ < 4; ++nf_) {                                  \
            acc[mf_][nf_] = __builtin_amdgcn_mfma_f32_16x16x32_bf16(         \
                ah_, BH[nf_], acc[mf_][nf_], 0, 0, 0);                       \
            acc[mf_][nf_] = __builtin_amdgcn_mfma_f32_16x16x32_bf16(         \
                ah_, BL[nf_], acc[mf_][nf_], 0, 0, 0);                       \
            acc[mf_][nf_] = __builtin_amdgcn_mfma_f32_16x16x32_bf16(         \
                al_, BH[nf_], acc[mf_][nf_], 0, 0, 0);                       \
        } } } while (0)

    for (int ch = 0; ch < 4; ++ch) {
        const int cb = cs * 128 + ch * 32;

        __syncthreads();
        #pragma unroll
        for (int it = 0; it < 5; ++it) {
            int v  = tid + it * 256;          // 0..1279
            int cg = v & 3, pl = v >> 2;      // pl 0..319
            int ty = pl >> 5, tx = pl & 31;
            int yi = ylo - 2 + ty, xi = tx - 2;
            bool ok = (yi >= 0) && (yi < 28) && (xi >= 0) && (xi < 28);
            const float* rp = rec + ((size_t)(b * 512 + cb + cg * 8)) * NPOS
                              + yi * 28 + xi;
            uint_t hp[4], lp[4];
            #pragma unroll
            for (int i = 0; i < 4; ++i) {
                float v0 = ok ? rp[(size_t)(2 * i) * NPOS] : 0.f;
                float v1 = ok ? rp[(size_t)(2 * i + 1) * NPOS] : 0.f;
                ushort_t h0 = bf16rne(v0);
                ushort_t l0 = bf16rne(v0 - ubf(h0));
                ushort_t h1 = bf16rne(v1);
                ushort_t l1 = bf16rne(v1 - ubf(h1));
                hp[i] = (uint_t)h0 | ((uint_t)h1 << 16);
                lp[i] = (uint_t)l0 | ((uint_t)l1 << 16);
            }
            uint4 hv = make_uint4(hp[0], hp[1], hp[2], hp[3]);
            uint4 lv = make_uint4(lp[0], lp[1], lp[2], lp[3]);
            *(uint4*)(sA + pl * 32 + cg * 8) = hv;
            *(uint4*)(sA + 10240 + pl * 32 + cg * 8) = lv;
        }
        __syncthreads();

        bf16x8 bh0[4], bl0[4], bh1[4], bl1[4];
        LOADB(bh0, bl0, 0, cb);
        for (int t = 0; t < 24; t += 2) {
            int t1 = t + 1, t2 = (t + 2 <= 24) ? t + 2 : 24;
            LOADB(bh1, bl1, t1, cb);
            TAPBODY(bh0, bl0, (t / 5) * 32 + (t % 5));
            LOADB(bh0, bl0, t2, cb);
            TAPBODY(bh1, bl1, (t1 / 5) * 32 + (t1 % 5));
        }
        TAPBODY(bh0, bl0, 4 * 32 + 4);
    }

    #pragma unroll
    for (int mf = 0; mf < 4; ++mf) {
        int prow = p0 + wm * 64 + mf * 16 + g * 4;
        #pragma unroll
        for (int nf = 0; nf < 4; ++nf) {
            int oc = oc0 + nf * 16 + m_in;
            #pragma unroll
            for (int r = 0; r < 4; ++r) {
                int pos = prow + r;
                if (pos < NPOS)
                    hpart[(((size_t)(cs * 4 + b) * NPOS + pos) << 8) + oc] =
                        acc[mf][nf][r];
            }
        }
    }
#undef LOADB
#undef TAPBODY
}

// ---------------------------------------------------------------------------
// 3. reduce partials + bias + channel-LN + GELU + 1x1(256->16) + tanh + clip
__global__ __launch_bounds__(256) void k_lnoff(const float* __restrict__ hpart,
                                               const float* __restrict__ b1,
                                               const float* __restrict__ g,
                                               const float* __restrict__ bb,
                                               const float* __restrict__ w2,
                                               const float* __restrict__ b2,
                                               const float* __restrict__ ref,
                                               float* __restrict__ loc) {
    const int pos = blockIdx.x, b = blockIdx.y, c = threadIdx.x;
    float v = b1[c];
    #pragma unroll
    for (int cs = 0; cs < 4; ++cs)
        v += hpart[((size_t)((cs * 4 + b) * NPOS + pos)) * 256 + c];

    float s1 = v, s2 = v * v;
    #pragma unroll
    for (int m = 32; m >= 1; m >>= 1) {
        s1 += __shfl_xor(s1, m);
        s2 += __shfl_xor(s2, m);
    }
    __shared__ float r1[4], r2[4];
    const int wv = c >> 6, ln = c & 63;
    if (ln == 0) { r1[wv] = s1; r2[wv] = s2; }
    __syncthreads();
    s1 = r1[0] + r1[1] + r1[2] + r1[3];
    s2 = r2[0] + r2[1] + r2[2] + r2[3];
    const float mu  = s1 * (1.f / 256.f);
    const float var = s2 * (1.f / 256.f) - mu * mu;
    const float rstd = 1.f / sqrtf(var + 1e-5f);
    const float xn = (v - mu) * rstd * g[c] + bb[c];
    const float ge = 0.5f * xn * (1.f + erff(xn * 0.70710678118654752f));

    __shared__ float ro[4][16];
    for (int o = 0; o < 16; ++o) {
        float pv = ge * w2[o * 256 + c];
        #pragma unroll
        for (int m = 32; m >= 1; m >>= 1) pv += __shfl_xor(pv, m);
        if (ln == 0) ro[wv][o] = pv;
    }
    __syncthreads();
    if (c < 16) {
        float off = ro[0][c] + ro[1][c] + ro[2][c] + ro[3][c] + b2[c];
        float t = tanhf(off);
        int hd = c >> 1, comp = c & 1;
        size_t li = ((size_t)((b * 8 + hd) * NPOS + pos)) * 2 + comp;
        float l = ref[li] + t;
        loc[li] = fminf(1.f, fmaxf(-1.f, l));
    }
}

// ---------------------------------------------------------------------------
// 4. bilinear grid_sample, zeros padding -> samp[32][32][784].
__global__ __launch_bounds__(256) void k_gsample(const float* __restrict__ x,
                                                 const float* __restrict__ loc,
                                                 float* __restrict__ samp) {
    int idx = blockIdx.x * 256 + threadIdx.x;      // 25,088 exact
    int pos = idx % NPOS;
    int bh  = idx / NPOS;
    float gx = loc[(size_t)idx * 2 + 0];
    float gy = loc[(size_t)idx * 2 + 1];
    float ix = (gx + 1.f) * 28.f - 0.5f;
    float iy = (gy + 1.f) * 28.f - 0.5f;
    float x0f = floorf(ix), y0f = floorf(iy);
    int x0 = (int)x0f, y0 = (int)y0f;
    float wx = ix - x0f, wy = iy - y0f;

    int xs[2] = { x0, x0 + 1 };
    int ys[2] = { y0, y0 + 1 };
    float wxs[2] = { 1.f - wx, wx };
    float wys[2] = { 1.f - wy, wy };
    int   cidx[4];
    float cw[4];
    #pragma unroll
    for (int a = 0; a < 2; ++a)
        #pragma unroll
        for (int bb2 = 0; bb2 < 2; ++bb2) {
            int yy = ys[a], xx = xs[bb2];
            bool inb = (xx >= 0) && (xx < W_) && (yy >= 0) && (yy < H_);
            int yyc = min(max(yy, 0), H_ - 1), xxc = min(max(xx, 0), W_ - 1);
            cidx[a * 2 + bb2] = yyc * W_ + xxc;
            cw[a * 2 + bb2] = inb ? (wys[a] * wxs[bb2]) : 0.f;
        }

    const float* xb = x + (size_t)bh * DPH * NS;
    #pragma unroll 4
    for (int c = 0; c < DPH; ++c) {
        const float* xc = xb + (size_t)c * NS;
        float v = cw[0] * xc[cidx[0]] + cw[1] * xc[cidx[1]]
                + cw[2] * xc[cidx[2]] + cw[3] * xc[cidx[3]];
        samp[((size_t)bh * DPH + c) * NPOS + pos] = v;
    }
}

// ---------------------------------------------------------------------------
// 5. 256->256 1x1 projection (q-proj: in2 = pos emb; o-proj: in2 = null).
__global__ __launch_bounds__(256) void k_proj256(const float* __restrict__ in1,
                                                 const float* __restrict__ in2,
                                                 const float* __restrict__ w,
                                                 const float* __restrict__ bias,
                                                 float* __restrict__ out) {
    __shared__ __align__(16) float wl[256 * 16];
    const int tid = threadIdx.x, ot = blockIdx.y, b = blockIdx.z;
    for (int i = tid; i < 4096; i += 256) {
        int oo = i >> 8, c = i & 255;
        wl[c * 16 + oo] = w[(ot * 16 + oo) * 256 + c];
    }
    int s = blockIdx.x * 256 + tid;
    const bool sv = (s < NS);
    const int se = sv ? s : (NS - 1);
    const float* p1 = in1 + (size_t)b * 256 * NS + se;
    const float* p2 = in2 ? (in2 + (size_t)b * 256 * NS + se) : nullptr;
    const bool has2 = (in2 != nullptr);

    float acc[16] = {};
    __syncthreads();
    for (int c = 0; c < 256; ++c) {
        float xv = p1[(size_t)c * NS];
        if (has2) xv += p2[(size_t)c * NS];
        #pragma unroll
        for (int og = 0; og < 4; ++og) {
            float4 w4 = *(const float4*)&wl[c * 16 + og * 4];
            acc[og * 4 + 0] = fmaf(xv, w4.x, acc[og * 4 + 0]);
            acc[og * 4 + 1] = fmaf(xv, w4.y, acc[og * 4 + 1]);
            acc[og * 4 + 2] = fmaf(xv, w4.z, acc[og * 4 + 2]);
            acc[og * 4 + 3] = fmaf(xv, w4.w, acc[og * 4 + 3]);
        }
    }
    if (sv) {
        #pragma unroll
        for (int oo = 0; oo < 16; ++oo) {
            int o = ot * 16 + oo;
            out[((size_t)b * 256 + o) * NS + s] = acc[oo] + bias[o];
        }
    }
}

// ---------------------------------------------------------------------------
// 6. k/v 32->32 projections -> bf16: ktb[bh][pos][32], vtb[bh][dph][pos].
__global__ __launch_bounds__(256) void k_kv(const float* __restrict__ samp,
                                            const float* __restrict__ kw,
                                            const float* __restrict__ kb,
                                            const float* __restrict__ vw,
                                            const float* __restrict__ vb,
                                            ushort_t* __restrict__ ktb,
                                            ushort_t* __restrict__ vtb) {
    __shared__ __align__(16) float kl[1024], vl[1024];
    const int tid = threadIdx.x;
    for (int i = tid; i < 1024; i += 256) {
        int o = i >> 5, c = i & 31;
        kl[c * 32 + o] = kw[i];
        vl[c * 32 + o] = vw[i];
    }
    __syncthreads();
    int idx = blockIdx.x * 256 + tid;   // 25,088 exact
    int pos = idx % NPOS;
    int bh  = idx / NPOS;
    const float* sp = samp + (size_t)bh * DPH * NPOS + pos;
    float ak[32] = {}, av[32] = {};
    for (int c = 0; c < 32; ++c) {
        float sv = sp[(size_t)c * NPOS];
        #pragma unroll
        for (int og = 0; og < 8; ++og) {
            float4 k4 = *(const float4*)&kl[c * 32 + og * 4];
            float4 v4 = *(const float4*)&vl[c * 32 + og * 4];
            ak[og * 4 + 0] = fmaf(sv, k4.x, ak[og * 4 + 0]);
            ak[og * 4 + 1] = fmaf(sv, k4.y, ak[og * 4 + 1]);
            ak[og * 4 + 2] = fmaf(sv, k4.z, ak[og * 4 + 2]);
            ak[og * 4 + 3] = fmaf(sv, k4.w, ak[og * 4 + 3]);
            av[og * 4 + 0] = fmaf(sv, v4.x, av[og * 4 + 0]);
            av[og * 4 + 1] = fmaf(sv, v4.y, av[og * 4 + 1]);
            av[og * 4 + 2] = fmaf(sv, v4.z, av[og * 4 + 2]);
            av[og * 4 + 3] = fmaf(sv, v4.w, av[og * 4 + 3]);
        }
    }
    // ktb: [bh][pos][32] bf16, 64B/thread contiguous
    uint_t kp[16];
    #pragma unroll
    for (int o = 0; o < 16; ++o)
        kp[o] = (uint_t)bf16rne(ak[2 * o] + kb[2 * o])
              | ((uint_t)bf16rne(ak[2 * o + 1] + kb[2 * o + 1]) << 16);
    uint4* kdst = (uint4*)(ktb + (size_t)idx * 32);
    kdst[0] = make_uint4(kp[0], kp[1], kp[2], kp[3]);
    kdst[1] = make_uint4(kp[4], kp[5], kp[6], kp[7]);
    kdst[2] = make_uint4(kp[8], kp[9], kp[10], kp[11]);
    kdst[3] = make_uint4(kp[12], kp[13], kp[14], kp[15]);
    // vtb: [bh][dph][784] bf16
    #pragma unroll
    for (int o = 0; o < 32; ++o)
        vtb[((size_t)bh * 32 + o) * NPOS + pos] = bf16rne(av[o] + vb[o]);
}

// ---------------------------------------------------------------------------
// 7. MFMA flash attention. grid (13 qtile, 32 bh), 256 thr = 4 waves.
//    Per wave: 64 q rows. S^T = mfma(K, Q) -> col(lane&15)=q, row=kv.
//    Softmax per-q is lane-local over 16 regs + 2 shfl_xor (g bits).
//    P^T -> wave-private LDS (bf16) -> B-frag of O^T = mfma(V^T, P^T).
__global__ __launch_bounds__(256) void k_attn_mfma(const float* __restrict__ qbuf,
                                                   const ushort_t* __restrict__ ktb,
                                                   const ushort_t* __restrict__ vtb,
                                                   float* __restrict__ out) {
    const int qt = blockIdx.x, bh = blockIdx.y;
    const int b = bh >> 3, head = bh & 7;
    const int tid = threadIdx.x, lane = tid & 63, wid = tid >> 6;
    const int n = lane & 15, g = lane >> 4;

    __shared__ __align__(16) ushort_t sQ[256 * 40];      // [q][dph], pad 40
    __shared__ __align__(16) ushort_t sP[4][64 * 72];    // per-wave [q][kv], pad 72

    const int q0 = qt * 256;
    {   // stage Q tile (bf16), row t per thread, 16 packed u32 LDS writes
        int qrow = q0 + tid; if (qrow > NS - 1) qrow = NS - 1;
        const float* qp = qbuf + ((size_t)(b * 256 + head * 32)) * NS + qrow;
        uint_t* dst = (uint_t*)(sQ + tid * 40);
        #pragma unroll
        for (int cp = 0; cp < 16; ++cp) {
            float v0 = qp[(size_t)(2 * cp) * NS];
            float v1 = qp[(size_t)(2 * cp + 1) * NS];
            dst[cp] = (uint_t)bf16rne(v0) | ((uint_t)bf16rne(v1) << 16);
        }
    }
    __syncthreads();

    // Q B-frags: lane n = q-in-frag, k = g*8.. (constant over kv loop)
    bf16x8 qf[4];
    #pragma unroll
    for (int nf = 0; nf < 4; ++nf)
        qf[nf] = *(const bf16x8*)(sQ + (wid * 64 + nf * 16 + n) * 40 + g * 8);

    const ushort_t* kbase = ktb + (size_t)bh * NPOS * 32;
    const ushort_t* vbase = vtb + (size_t)bh * 32 * NPOS;
    ushort_t* myP = sP[wid];

    f32x4 o_acc[2][4];
    #pragma unroll
    for (int i = 0; i < 2; ++i)
        #pragma unroll
        for (int j = 0; j < 4; ++j)
            o_acc[i][j] = (f32x4){0.f, 0.f, 0.f, 0.f};
    float mrun[4] = {-1e30f, -1e30f, -1e30f, -1e30f};
    float lrun[4] = {0.f, 0.f, 0.f, 0.f};

    // ---- 12 full kv tiles of 64
    for (int t = 0; t < 12; ++t) {
        const int kvt = t * 64;
        // K A-frags: perfectly coalesced (64 lanes = contiguous 1KB)
        bf16x8 kf[4];
        #pragma unroll
        for (int mf = 0; mf < 4; ++mf)
            kf[mf] = *(const bf16x8*)(kbase + (size_t)(kvt + mf * 16 + n) * 32 + g * 8);
        // V^T A-frags
        bf16x8 vf[2][2];
        #pragma unroll
        for (int mv = 0; mv < 2; ++mv)
            #pragma unroll
            for (int kc = 0; kc < 2; ++kc)
                vf[mv][kc] = *(const bf16x8*)(vbase + (size_t)(mv * 16 + n) * NPOS
                                              + kvt + kc * 32 + g * 8);

        // S^T tile
        f32x4 acc[4][4];
        #pragma unroll
        for (int mf = 0; mf < 4; ++mf)
            #pragma unroll
            for (int nf = 0; nf < 4; ++nf)
                acc[mf][nf] = __builtin_amdgcn_mfma_f32_16x16x32_bf16(
                    kf[mf], qf[nf], (f32x4){0.f, 0.f, 0.f, 0.f}, 0, 0, 0);

        // online softmax per q (lane-local + 2 shfl over g bits)
        #pragma unroll
        for (int nf = 0; nf < 4; ++nf) {
            float s[4][4];
            float tmax = -1e30f;
            #pragma unroll
            for (int mf = 0; mf < 4; ++mf)
                #pragma unroll
                for (int r = 0; r < 4; ++r) {
                    s[mf][r] = acc[mf][nf][r] * (1.f / 16.f);
                    tmax = fmaxf(tmax, s[mf][r]);
                }
            tmax = fmaxf(tmax, __shfl_xor(tmax, 16));
            tmax = fmaxf(tmax, __shfl_xor(tmax, 32));
            float mnew = fmaxf(mrun[nf], tmax);
            float corr = __expf(mrun[nf] - mnew);
            mrun[nf] = mnew;
            float psum = 0.f;
            float p[4][4];
            #pragma unroll
            for (int mf = 0; mf < 4; ++mf)
                #pragma unroll
                for (int r = 0; r < 4; ++r) {
                    p[mf][r] = __expf(s[mf][r] - mnew);
                    psum += p[mf][r];
                }
            psum += __shfl_xor(psum, 16);
            psum += __shfl_xor(psum, 32);
            lrun[nf] = lrun[nf] * corr + psum;
            #pragma unroll
            for (int mv = 0; mv < 2; ++mv)
                #pragma unroll
                for (int r = 0; r < 4; ++r)
                    o_acc[mv][nf][r] *= corr;
            // pack P -> LDS [q][kv] (cols 16mf+4g..+3), b64 writes
            #pragma unroll
            for (int mf = 0; mf < 4; ++mf) {
                uint_t lo = cvtpk_bf16(p[mf][0], p[mf][1]);
                uint_t hi = cvtpk_bf16(p[mf][2], p[mf][3]);
                *(uint2*)(myP + (nf * 16 + n) * 72 + mf * 16 + g * 4) =
                    make_uint2(lo, hi);
            }
        }

        // O^T += V^T . P^T
        #pragma unroll
        for (int kc = 0; kc < 2; ++kc)
            #pragma unroll
            for (int nf = 0; nf < 4; ++nf) {
                bf16x8 pb = *(const bf16x8*)(myP + (nf * 16 + n) * 72
                                             + kc * 32 + g * 8);
                #pragma unroll
                for (int mv = 0; mv < 2; ++mv)
                    o_acc[mv][nf] = __builtin_amdgcn_mfma_f32_16x16x32_bf16(
                        vf[mv][kc], pb, o_acc[mv][nf], 0, 0, 0);
            }
    }

    // ---- epilog tile: kv 768..783 (16 rows -> only mf=0)
    {
        const int kvt = 768;
        bf16x8 kf0 = *(const bf16x8*)(kbase + (size_t)(kvt + n) * 32 + g * 8);
        bf16x8 vf[2];
        int kvo = kvt + g * 8; if (kvo > 776) kvo = 776;   // clamp (P=0 there)
        #pragma unroll
        for (int mv = 0; mv < 2; ++mv)
            vf[mv] = *(const bf16x8*)(vbase + (size_t)(mv * 16 + n) * NPOS + kvo);

        f32x4 acc0[4];
        #pragma unroll
        for (int nf = 0; nf < 4; ++nf)
            acc0[nf] = __builtin_amdgcn_mfma_f32_16x16x32_bf16(
                kf0, qf[nf], (f32x4){0.f, 0.f, 0.f, 0.f}, 0, 0, 0);

        #pragma unroll
        for (int nf = 0; nf < 4; ++nf) {
            float s[4], tmax = -1e30f;
            #pragma unroll
            for (int r = 0; r < 4; ++r) {
                s[r] = acc0[nf][r] * (1.f / 16.f);
                tmax = fmaxf(tmax, s[r]);
            }
            tmax = fmaxf(tmax, __shfl_xor(tmax, 16));
            tmax = fmaxf(tmax, __shfl_xor(tmax, 32));
            float mnew = fmaxf(mrun[nf], tmax);
            float corr = __expf(mrun[nf] - mnew);
            mrun[nf] = mnew;
            float psum = 0.f, p[4];
            #pragma unroll
            for (int r = 0; r < 4; ++r) { p[r] = __expf(s[r] - mnew); psum += p[r]; }
            psum += __shfl_xor(psum, 16);
            psum += __shfl_xor(psum, 32);
            lrun[nf] = lrun[nf] * corr + psum;
            #pragma unroll
            for (int mv = 0; mv < 2; ++mv)
                #pragma unroll
                for (int r = 0; r < 4; ++r)
                    o_acc[mv][nf][r] *= corr;
            uint_t lo = cvtpk_bf16(p[0], p[1]);
            uint_t hi = cvtpk_bf16(p[2], p[3]);
            *(uint2*)(myP + (nf * 16 + n) * 72 + g * 4) = make_uint2(lo, hi);
            *(uint2*)(myP + (nf * 16 + n) * 72 + 16 + g * 4) = make_uint2(0u, 0u);
        }
        #pragma unroll
        for (int nf = 0; nf < 4; ++nf) {
            bf16x8 pb = *(const bf16x8*)(myP + (nf * 16 + n) * 72 + g * 8);
            #pragma unroll
            for (int mv = 0; mv < 2; ++mv)
                o_acc[mv][nf] = __builtin_amdgcn_mfma_f32_16x16x32_bf16(
                    vf[mv], pb, o_acc[mv][nf], 0, 0, 0);
        }
    }

    // ---- normalize + store: out[(b*256 + head*32 + dph)*NS + q]
    float* obase = out + ((size_t)(b * 256 + head * 32)) * NS;
    #pragma unroll
    for (int nf = 0; nf < 4; ++nf) {
        float inv = 1.f / lrun[nf];
        int qpos = q0 + wid * 64 + nf * 16 + n;
        if (qpos < NS) {
            #pragma unroll
            for (int mv = 0; mv < 2; ++mv)
                #pragma unroll
                for (int r = 0; r < 4; ++r) {
                    int dph = mv * 16 + g * 4 + r;
                    obase[(size_t)dph * NS + qpos] = o_acc[mv][nf][r] * inv;
                }
        }
    }
}

// ---------------------------------------------------------------------------
extern "C" void kernel_launch(void* const* d_in, const int* in_sizes, int n_in,
                              void* d_out, int out_size, void* d_ws, size_t ws_size,
                              hipStream_t stream) {
    const float* query = (const float*)d_in[0];
    const float* x     = (const float*)d_in[1];
    const float* refp  = (const float*)d_in[2];
    const float* pe    = (const float*)d_in[3];
    const float* w1    = (const float*)d_in[4];
    const float* b1    = (const float*)d_in[5];
    const float* lng   = (const float*)d_in[6];
    const float* lnb   = (const float*)d_in[7];
    const float* w2    = (const float*)d_in[8];
    const float* b2    = (const float*)d_in[9];
    const float* qw    = (const float*)d_in[10];
    const float* qb    = (const float*)d_in[11];
    const float* kw    = (const float*)d_in[12];
    const float* kb    = (const float*)d_in[13];
    const float* vw    = (const float*)d_in[14];
    const float* vb    = (const float*)d_in[15];
    const float* ow    = (const float*)d_in[16];
    const float* ob    = (const float*)d_in[17];

    float* ws  = (float*)d_ws;
    float* out = (float*)d_out;

    float* rec     = ws + OFF_REC;
    float* hpart   = ws + OFF_HPART;
    float* attnout = ws + OFF_ATTNOUT;   // aliases rec+hpart (both dead by then)
    float* loc     = ws + OFF_LOC;
    float* samp    = ws + OFF_SAMP;
    float* qbuf    = ws + OFF_Q;
    ushort_t* ktb  = (ushort_t*)(ws + OFF_KTB);
    ushort_t* vtb  = (ushort_t*)(ws + OFF_VTB);
    ushort_t* wrep_hi = (ushort_t*)(ws + OFF_WREP);
    ushort_t* wrep_lo = wrep_hi + 3276800u;

    k_pool<<<6272, 256, 0, stream>>>(query, x, rec);
    k_wrepack<<<512, 256, 0, stream>>>(w1, wrep_hi, wrep_lo);
    k_conv_mfma<<<dim3(7, 8, 4), 256, 0, stream>>>(rec, wrep_hi, wrep_lo, hpart);
    k_lnoff<<<dim3(784, 4), 256, 0, stream>>>(hpart, b1, lng, lnb, w2, b2, refp, loc);
    k_gsample<<<98, 256, 0, stream>>>(x, loc, samp);
    k_proj256<<<dim3(13, 16, 4), 256, 0, stream>>>(query, pe, qw, qb, qbuf);
    k_kv<<<98, 256, 0, stream>>>(samp, kw, kb, vw, vb, ktb, vtb);
    k_attn_mfma<<<dim3(13, 32), 256, 0, stream>>>(qbuf, ktb, vtb, attnout);
    k_proj256<<<dim3(13, 16, 4), 256, 0, stream>>>(attnout, nullptr, ow, ob, out);
}

// Round 4
// 270.031 us; speedup vs baseline: 3.5153x; 1.3460x over previous
//
#include <hip/hip_runtime.h>
#include <hip/hip_bf16.h>

// Problem constants
#define B_    4
#define D_    256
#define H_    56
#define W_    56
#define NH_   28
#define NW_   28
#define HEADS 8
#define DPH   32
#define NPOS  784      // 28*28
#define NS    3136     // 56*56

typedef unsigned short ushort_t;
typedef unsigned int uint_t;
typedef __attribute__((ext_vector_type(8))) short bf16x8;
typedef __attribute__((ext_vector_type(4))) float f32x4;

// ws layout (float offsets)
#define OFF_REC     0u          // packed u32 [4][512][784]      1,605,632
#define OFF_HPART   1605632u    // f32 [4cs][4b][784][256]       3,211,264
#define OFF_WREPC   4816896u    // conv wrep hi+lo (6,553,600 us) 3,276,800
#define OFF_LOC     8093696u    // f32 [32][784][2]              50,176
#define OFF_SAMP    8143872u    // f32 [32][32][784]             802,816
#define OFF_KTB     8946688u    // bf16 [32][784][32]            401,408
#define OFF_VTB     9348096u    // bf16 [32][32][784]+pad        401,472
#define OFF_W256    9749568u    // qw/ow hi+lo (262,144 us)      131,072
// aliases (lifetime-disjoint):
#define OFF_QPE     4816896u    // packed u32 [4][3136][256] (alias WREPC, dead after conv)
#define OFF_QBF     0u          // bf16 [4][3136][256] (alias REC, dead after conv)
#define OFF_ATTNT   1605632u    // packed u32 [4][3136][256] (alias HPART, dead after lnoff)
// total 9,880,640 floats = 39.5 MB

__device__ __forceinline__ ushort_t bf16rne(float f) {
    uint_t u = __float_as_uint(f);
    return (ushort_t)((u + 0x7FFFu + ((u >> 16) & 1u)) >> 16);
}
__device__ __forceinline__ float ubf(ushort_t h) {
    return __uint_as_float(((uint_t)h) << 16);
}
__device__ __forceinline__ uint_t packsplit(float v) {
    ushort_t hi = bf16rne(v);
    ushort_t lo = bf16rne(v - ubf(hi));
    return ((uint_t)hi << 16) | (uint_t)lo;
}
__device__ __forceinline__ uint_t cvtpk_bf16(float a, float b) {
    uint_t r;
    asm("v_cvt_pk_bf16_f32 %0, %1, %2" : "=v"(r) : "v"(a), "v"(b));
    return r;
}
__device__ __forceinline__ bf16x8 mk8(uint_t a, uint_t b, uint_t c, uint_t d) {
    union { uint_t u[4]; bf16x8 v; } x;
    x.u[0] = a; x.u[1] = b; x.u[2] = c; x.u[3] = d;
    return x.v;
}

// ---------------------------------------------------------------------------
// 1. 2x2 avg-pool of query|x -> rec packed-split u32 [4][512][784]
__global__ __launch_bounds__(256) void k_pool(const float* __restrict__ q,
                                              const float* __restrict__ x,
                                              uint_t* __restrict__ rec) {
    int idx = blockIdx.x * 256 + threadIdx.x;      // 1,605,632 exact
    int j = idx % NW_;
    int i = (idx / NW_) % NH_;
    int c = (idx / NPOS) % 512;
    int b = idx / (NPOS * 512);
    const float* src = (c < 256) ? q : x;
    int cc = (c < 256) ? c : (c - 256);
    const float* p = src + ((size_t)(b * 256 + cc) * H_ + i * 2) * W_ + j * 2;
    float v = 0.25f * (p[0] + p[1] + p[W_] + p[W_ + 1]);
    rec[idx] = packsplit(v);
}

// ---------------------------------------------------------------------------
// 1b. repack conv weights -> wrep_hi/lo[tap][oc][c] bf16 split.
__global__ __launch_bounds__(256) void k_wrepack(const float* __restrict__ w1,
                                                 ushort_t* __restrict__ wh,
                                                 ushort_t* __restrict__ wl) {
    int idx = blockIdx.x * 256 + threadIdx.x;  // 131072 = oc*512 + c
    const float* wp = w1 + (size_t)idx * 25;
    int oc = idx >> 9, c = idx & 511;
    #pragma unroll 5
    for (int tap = 0; tap < 25; ++tap) {
        float v = wp[tap];
        ushort_t h = bf16rne(v);
        ushort_t l = bf16rne(v - ubf(h));
        size_t o = ((size_t)tap * 256 + oc) * 512 + c;
        wh[o] = h;
        wl[o] = l;
    }
}

// 1c. repack q_w and o_w -> [oc][c] hi/lo
__global__ __launch_bounds__(256) void k_wrep256(const float* __restrict__ qw,
                                                 const float* __restrict__ ow,
                                                 ushort_t* __restrict__ w256) {
    int idx = blockIdx.x * 256 + threadIdx.x;   // 65536
    float qv = qw[idx], ov = ow[idx];
    ushort_t qh = bf16rne(qv);
    w256[idx] = qh;
    w256[idx + 65536] = bf16rne(qv - ubf(qh));
    ushort_t oh = bf16rne(ov);
    w256[idx + 131072] = oh;
    w256[idx + 196608] = bf16rne(ov - ubf(oh));
}

// ---------------------------------------------------------------------------
// 2. conv5x5 (512->256) as 25 shifted MFMA GEMMs, bf16 2-way split.
//    Flat grid 224 = 28 u * 8 ntcs; ntcs = bid&7 -> XCD-affine weight slices.
//    512 thr = 8 waves: wm=wid&1 (pos-64 group), wn=wid>>1 (oc-32 group).
__global__ __launch_bounds__(512) void k_conv_mfma(const uint_t* __restrict__ rec,
                                                   const ushort_t* __restrict__ wrep_hi,
                                                   float* __restrict__ hpart) {
    const int bid = blockIdx.x;
    const int ntcs = bid & 7;
    const int u = bid >> 3;              // 0..27
    const int mt = u % 7;
    const int b  = u / 7;
    const int nt = ntcs & 1;
    const int cs = ntcs >> 1;

    const int tid  = threadIdx.x;
    const int lane = tid & 63;
    const int wid  = tid >> 6;
    const int wm = wid & 1, wn = wid >> 1;    // 2 pos-groups x 4 oc-groups
    const int m_in = lane & 15, g = lane >> 4;

    const int p0  = mt * 128;
    const int ylo = p0 / 28;

    // sA: [0..10239] = hi [320 plin][32 c] (XOR-swizzled slots), +10240 = lo
    __shared__ __align__(16) ushort_t sA[20480];

    int plinb[4];
    #pragma unroll
    for (int mf = 0; mf < 4; ++mf) {
        int p = p0 + wm * 64 + mf * 16 + m_in;
        int y = p / 28, xx = p - y * 28;
        plinb[mf] = (y - ylo) * 32 + xx;
    }

    const int oc0 = nt * 128 + wn * 32;
    const ushort_t* bp[2];
    #pragma unroll
    for (int nf = 0; nf < 2; ++nf) {
        int oc = oc0 + nf * 16 + m_in;
        bp[nf] = wrep_hi + ((size_t)oc << 9) + (g << 3);
    }

    f32x4 acc[4][2];
    #pragma unroll
    for (int i = 0; i < 4; ++i)
        #pragma unroll
        for (int j = 0; j < 2; ++j)
            acc[i][j] = (f32x4){0.f, 0.f, 0.f, 0.f};

#define LOADB(BH, BL, TAP, CB) do {                                          \
    size_t tof_ = (size_t)(TAP) * 131072 + (CB);                             \
    _Pragma("unroll")                                                        \
    for (int nf_ = 0; nf_ < 2; ++nf_) {                                      \
        BH[nf_] = *(const bf16x8*)(bp[nf_] + tof_);                          \
        BL[nf_] = *(const bf16x8*)(bp[nf_] + tof_ + 3276800u);               \
    } } while (0)

#define TAPBODY(BH, BL, TOFF) do {                                           \
    int to_ = (TOFF);                                                        \
    _Pragma("unroll")                                                        \
    for (int mf_ = 0; mf_ < 4; ++mf_) {                                      \
        const int pl_ = plinb[mf_] + to_;                                    \
        const int ao_ = (pl_ << 5) + ((g ^ ((pl_ >> 1) & 3)) << 3);          \
        bf16x8 ah_ = *(const bf16x8*)(sA + ao_);                             \
        bf16x8 al_ = *(const bf16x8*)(sA + 10240 + ao_);                     \
        _Pragma("unroll")                                                    \
        for (int nf_ = 0; nf_ < 2; ++nf_) {                                  \
            acc[mf_][nf_] = __builtin_amdgcn_mfma_f32_16x16x32_bf16(         \
                ah_, BH[nf_], acc[mf_][nf_], 0, 0, 0);                       \
            acc[mf_][nf_] = __builtin_amdgcn_mfma_f32_16x16x32_bf16(         \
                ah_, BL[nf_], acc[mf_][nf_], 0, 0, 0);                       \
            acc[mf_][nf_] = __builtin_amdgcn_mfma_f32_16x16x32_bf16(         \
                al_, BH[nf_], acc[mf_][nf_], 0, 0, 0);                       \
        } } } while (0)

    for (int ch = 0; ch < 4; ++ch) {
        const int cb = cs * 128 + ch * 32;

        __syncthreads();
        #pragma unroll
        for (int it = 0; it < 3; ++it) {
            int v = tid + it * 512;           // 0..1279
            if (v < 1280) {
                int cg = v & 3, pl = v >> 2;  // pl 0..319
                int ty = pl >> 5, tx = pl & 31;
                int yi = ylo - 2 + ty, xi = tx - 2;
                bool ok = (yi >= 0) && (yi < 28) && (xi >= 0) && (xi < 28);
                const uint_t* rp = rec + ((size_t)(b * 512 + cb + cg * 8)) * NPOS
                                  + yi * 28 + xi;
                uint_t rr[8];
                #pragma unroll
                for (int i = 0; i < 8; ++i) rr[i] = ok ? rp[(size_t)i * NPOS] : 0u;
                uint_t hw[4], lw[4];
                #pragma unroll
                for (int j = 0; j < 4; ++j) {
                    hw[j] = (rr[2 * j] >> 16) | (rr[2 * j + 1] & 0xFFFF0000u);
                    lw[j] = (rr[2 * j] & 0xFFFFu) | (rr[2 * j + 1] << 16);
                }
                int cw = cg ^ ((pl >> 1) & 3);
                *(uint4*)(sA + pl * 32 + cw * 8) = make_uint4(hw[0], hw[1], hw[2], hw[3]);
                *(uint4*)(sA + 10240 + pl * 32 + cw * 8) = make_uint4(lw[0], lw[1], lw[2], lw[3]);
            }
        }
        __syncthreads();

        bf16x8 bh0[2], bl0[2], bh1[2], bl1[2];
        LOADB(bh0, bl0, 0, cb);
        for (int t = 0; t < 24; t += 2) {
            int t1 = t + 1, t2 = (t + 2 <= 24) ? t + 2 : 24;
            LOADB(bh1, bl1, t1, cb);
            TAPBODY(bh0, bl0, (t / 5) * 32 + (t % 5));
            LOADB(bh0, bl0, t2, cb);
            TAPBODY(bh1, bl1, (t1 / 5) * 32 + (t1 % 5));
        }
        TAPBODY(bh0, bl0, 4 * 32 + 4);
    }

    #pragma unroll
    for (int mf = 0; mf < 4; ++mf) {
        int prow = p0 + wm * 64 + mf * 16 + g * 4;
        #pragma unroll
        for (int nf = 0; nf < 2; ++nf) {
            int oc = oc0 + nf * 16 + m_in;
            #pragma unroll
            for (int r = 0; r < 4; ++r) {
                int pos = prow + r;
                if (pos < NPOS)
                    hpart[(((size_t)(cs * 4 + b) * NPOS + pos) << 8) + oc] =
                        acc[mf][nf][r];
            }
        }
    }
#undef LOADB
#undef TAPBODY
}

// ---------------------------------------------------------------------------
// 3. reduce partials + bias + channel-LN + GELU + 1x1(256->16) + tanh + clip
__global__ __launch_bounds__(256) void k_lnoff(const float* __restrict__ hpart,
                                               const float* __restrict__ b1,
                                               const float* __restrict__ g,
                                               const float* __restrict__ bb,
                                               const float* __restrict__ w2,
                                               const float* __restrict__ b2,
                                               const float* __restrict__ ref,
                                               float* __restrict__ loc) {
    const int pos = blockIdx.x, b = blockIdx.y, c = threadIdx.x;
    float v = b1[c];
    #pragma unroll
    for (int cs = 0; cs < 4; ++cs)
        v += hpart[((size_t)((cs * 4 + b) * NPOS + pos)) * 256 + c];

    float s1 = v, s2 = v * v;
    #pragma unroll
    for (int m = 32; m >= 1; m >>= 1) {
        s1 += __shfl_xor(s1, m);
        s2 += __shfl_xor(s2, m);
    }
    __shared__ float r1[4], r2[4];
    const int wv = c >> 6, ln = c & 63;
    if (ln == 0) { r1[wv] = s1; r2[wv] = s2; }
    __syncthreads();
    s1 = r1[0] + r1[1] + r1[2] + r1[3];
    s2 = r2[0] + r2[1] + r2[2] + r2[3];
    const float mu  = s1 * (1.f / 256.f);
    const float var = s2 * (1.f / 256.f) - mu * mu;
    const float rstd = 1.f / sqrtf(var + 1e-5f);
    const float xn = (v - mu) * rstd * g[c] + bb[c];
    const float ge = 0.5f * xn * (1.f + erff(xn * 0.70710678118654752f));

    __shared__ float ro[4][16];
    for (int o = 0; o < 16; ++o) {
        float pv = ge * w2[o * 256 + c];
        #pragma unroll
        for (int m = 32; m >= 1; m >>= 1) pv += __shfl_xor(pv, m);
        if (ln == 0) ro[wv][o] = pv;
    }
    __syncthreads();
    if (c < 16) {
        float off = ro[0][c] + ro[1][c] + ro[2][c] + ro[3][c] + b2[c];
        float t = tanhf(off);
        int hd = c >> 1, comp = c & 1;
        size_t li = ((size_t)((b * 8 + hd) * NPOS + pos)) * 2 + comp;
        float l = ref[li] + t;
        loc[li] = fminf(1.f, fmaxf(-1.f, l));
    }
}

// ---------------------------------------------------------------------------
// 4. bilinear grid_sample, zeros padding -> samp[32][32][784].
__global__ __launch_bounds__(256) void k_gsample(const float* __restrict__ x,
                                                 const float* __restrict__ loc,
                                                 float* __restrict__ samp) {
    int idx = blockIdx.x * 256 + threadIdx.x;      // 25,088 exact
    int pos = idx % NPOS;
    int bh  = idx / NPOS;
    float gx = loc[(size_t)idx * 2 + 0];
    float gy = loc[(size_t)idx * 2 + 1];
    float ix = (gx + 1.f) * 28.f - 0.5f;
    float iy = (gy + 1.f) * 28.f - 0.5f;
    float x0f = floorf(ix), y0f = floorf(iy);
    int x0 = (int)x0f, y0 = (int)y0f;
    float wx = ix - x0f, wy = iy - y0f;

    int xs[2] = { x0, x0 + 1 };
    int ys[2] = { y0, y0 + 1 };
    float wxs[2] = { 1.f - wx, wx };
    float wys[2] = { 1.f - wy, wy };
    int   cidx[4];
    float cw[4];
    #pragma unroll
    for (int a = 0; a < 2; ++a)
        #pragma unroll
        for (int bb2 = 0; bb2 < 2; ++bb2) {
            int yy = ys[a], xx = xs[bb2];
            bool inb = (xx >= 0) && (xx < W_) && (yy >= 0) && (yy < H_);
            int yyc = min(max(yy, 0), H_ - 1), xxc = min(max(xx, 0), W_ - 1);
            cidx[a * 2 + bb2] = yyc * W_ + xxc;
            cw[a * 2 + bb2] = inb ? (wys[a] * wxs[bb2]) : 0.f;
        }

    const float* xb = x + (size_t)bh * DPH * NS;
    #pragma unroll 4
    for (int c = 0; c < DPH; ++c) {
        const float* xc = xb + (size_t)c * NS;
        float v = cw[0] * xc[cidx[0]] + cw[1] * xc[cidx[1]]
                + cw[2] * xc[cidx[2]] + cw[3] * xc[cidx[3]];
        samp[((size_t)bh * DPH + c) * NPOS + pos] = v;
    }
}

// ---------------------------------------------------------------------------
// 4b. qpe = (query + pos_emb) transposed to [b][s][256] packed-split u32.
//     LDS-transposed in two c-halves of 128.
__global__ __launch_bounds__(256) void k_qpe(const float* __restrict__ q,
                                             const float* __restrict__ pe,
                                             uint_t* __restrict__ qpe) {
    const int st = blockIdx.x, b = blockIdx.y;
    const int s0 = st * 64;
    __shared__ uint_t T[64 * 129];
    const int l = threadIdx.x & 63, w = threadIdx.x >> 6;

    for (int half = 0; half < 2; ++half) {
        #pragma unroll 4
        for (int cc = 0; cc < 32; ++cc) {
            int c = half * 128 + w * 32 + cc;
            size_t gi = (size_t)(b * 256 + c) * NS + s0 + l;
            T[l * 129 + w * 32 + cc] = packsplit(q[gi] + pe[gi]);
        }
        __syncthreads();
        {
            int s = threadIdx.x >> 2, q4 = threadIdx.x & 3;
            uint_t* dst = qpe + ((size_t)b * NS + s0 + s) * 256 + half * 128 + q4 * 32;
            const uint_t* src = T + s * 129 + q4 * 32;
            #pragma unroll
            for (int i = 0; i < 8; ++i) {
                uint_t a0 = src[i * 4], a1 = src[i * 4 + 1];
                uint_t a2 = src[i * 4 + 2], a3 = src[i * 4 + 3];
                *(uint4*)(dst + i * 4) = make_uint4(a0, a1, a2, a3);
            }
        }
        __syncthreads();
    }
}

// ---------------------------------------------------------------------------
// 5. streaming MFMA 256x256 projection. A = weights [oc][c] hi/lo (global),
//    B = packed-split input^T [b][s][256] (global), 3-MFMA split, no LDS,
//    no barriers. MODE 0: out bf16 [b][s][256] (+bias)  (q-proj -> attn Q)
//    MODE 1: out f32 [b][256][3136] (+bias)             (o-proj -> d_out)
template<int MODE>
__global__ __launch_bounds__(256) void k_proj(const uint_t* __restrict__ inT,
                                              const ushort_t* __restrict__ wh,
                                              const ushort_t* __restrict__ wl,
                                              const float* __restrict__ bias,
                                              float* __restrict__ outf,
                                              ushort_t* __restrict__ outb) {
    const int st = blockIdx.x, og = blockIdx.y, b = blockIdx.z;
    const int tid = threadIdx.x, lane = tid & 63, wid = tid >> 6;
    const int wsg = wid & 1, wo = wid >> 1;
    const int n = lane & 15, g = lane >> 4;
    const int s0 = st * 128 + wsg * 64;
    const int oc0 = og * 128 + wo * 64;
    const uint_t* ibase = inT + (size_t)b * NS * 256;

    int srow[4];
    #pragma unroll
    for (int nf = 0; nf < 4; ++nf)
        srow[nf] = min(s0 + nf * 16 + n, NS - 1);

    f32x4 acc[4][4];
    #pragma unroll
    for (int i = 0; i < 4; ++i)
        #pragma unroll
        for (int j = 0; j < 4; ++j)
            acc[i][j] = (f32x4){0.f, 0.f, 0.f, 0.f};

    #pragma unroll 2
    for (int kf = 0; kf < 8; ++kf) {
        const int ko = kf * 32 + g * 8;
        bf16x8 awh[4], awl[4];
        #pragma unroll
        for (int mf = 0; mf < 4; ++mf) {
            size_t a = (size_t)(oc0 + mf * 16 + n) * 256 + ko;
            awh[mf] = *(const bf16x8*)(wh + a);
            awl[mf] = *(const bf16x8*)(wl + a);
        }
        bf16x8 bh[4], bl[4];
        #pragma unroll
        for (int nf = 0; nf < 4; ++nf) {
            const uint4* p = (const uint4*)(ibase + (size_t)srow[nf] * 256 + ko);
            uint4 u = p[0], v = p[1];
            uint_t h0 = (u.x >> 16) | (u.y & 0xFFFF0000u);
            uint_t h1 = (u.z >> 16) | (u.w & 0xFFFF0000u);
            uint_t h2 = (v.x >> 16) | (v.y & 0xFFFF0000u);
            uint_t h3 = (v.z >> 16) | (v.w & 0xFFFF0000u);
            uint_t l0 = (u.x & 0xFFFFu) | (u.y << 16);
            uint_t l1 = (u.z & 0xFFFFu) | (u.w << 16);
            uint_t l2 = (v.x & 0xFFFFu) | (v.y << 16);
            uint_t l3 = (v.z & 0xFFFFu) | (v.w << 16);
            bh[nf] = mk8(h0, h1, h2, h3);
            bl[nf] = mk8(l0, l1, l2, l3);
        }
        #pragma unroll
        for (int mf = 0; mf < 4; ++mf)
            #pragma unroll
            for (int nf = 0; nf < 4; ++nf) {
                acc[mf][nf] = __builtin_amdgcn_mfma_f32_16x16x32_bf16(
                    awh[mf], bh[nf], acc[mf][nf], 0, 0, 0);
                acc[mf][nf] = __builtin_amdgcn_mfma_f32_16x16x32_bf16(
                    awh[mf], bl[nf], acc[mf][nf], 0, 0, 0);
                acc[mf][nf] = __builtin_amdgcn_mfma_f32_16x16x32_bf16(
                    awl[mf], bh[nf], acc[mf][nf], 0, 0, 0);
            }
    }

    #pragma unroll
    for (int mf = 0; mf < 4; ++mf) {
        const int ocr = oc0 + mf * 16 + g * 4;
        float bs[4];
        #pragma unroll
        for (int r = 0; r < 4; ++r) bs[r] = bias[ocr + r];
        #pragma unroll
        for (int nf = 0; nf < 4; ++nf) {
            int sc = s0 + nf * 16 + n;
            if (sc < NS) {
                if (MODE == 0) {
                    uint_t p0 = (uint_t)bf16rne(acc[mf][nf][0] + bs[0])
                              | ((uint_t)bf16rne(acc[mf][nf][1] + bs[1]) << 16);
                    uint_t p1 = (uint_t)bf16rne(acc[mf][nf][2] + bs[2])
                              | ((uint_t)bf16rne(acc[mf][nf][3] + bs[3]) << 16);
                    *(uint2*)(outb + ((size_t)b * NS + sc) * 256 + ocr) =
                        make_uint2(p0, p1);
                } else {
                    #pragma unroll
                    for (int r = 0; r < 4; ++r)
                        outf[(size_t)(b * 256 + ocr + r) * NS + sc] =
                            acc[mf][nf][r] + bs[r];
                }
            }
        }
    }
}

// ---------------------------------------------------------------------------
// 6. k/v 32->32 projections -> bf16: ktb[bh][pos][32], vtb[bh][dph][pos].
__global__ __launch_bounds__(256) void k_kv(const float* __restrict__ samp,
                                            const float* __restrict__ kw,
                                            const float* __restrict__ kb,
                                            const float* __restrict__ vw,
                                            const float* __restrict__ vb,
                                            ushort_t* __restrict__ ktb,
                                            ushort_t* __restrict__ vtb) {
    __shared__ __align__(16) float kl[1024], vl[1024];
    const int tid = threadIdx.x;
    for (int i = tid; i < 1024; i += 256) {
        int o = i >> 5, c = i & 31;
        kl[c * 32 + o] = kw[i];
        vl[c * 32 + o] = vw[i];
    }
    __syncthreads();
    int idx = blockIdx.x * 256 + tid;   // 25,088 exact
    int pos = idx % NPOS;
    int bh  = idx / NPOS;
    const float* sp = samp + (size_t)bh * DPH * NPOS + pos;
    float ak[32] = {}, av[32] = {};
    for (int c = 0; c < 32; ++c) {
        float sv = sp[(size_t)c * NPOS];
        #pragma unroll
        for (int og = 0; og < 8; ++og) {
            float4 k4 = *(const float4*)&kl[c * 32 + og * 4];
            float4 v4 = *(const float4*)&vl[c * 32 + og * 4];
            ak[og * 4 + 0] = fmaf(sv, k4.x, ak[og * 4 + 0]);
            ak[og * 4 + 1] = fmaf(sv, k4.y, ak[og * 4 + 1]);
            ak[og * 4 + 2] = fmaf(sv, k4.z, ak[og * 4 + 2]);
            ak[og * 4 + 3] = fmaf(sv, k4.w, ak[og * 4 + 3]);
            av[og * 4 + 0] = fmaf(sv, v4.x, av[og * 4 + 0]);
            av[og * 4 + 1] = fmaf(sv, v4.y, av[og * 4 + 1]);
            av[og * 4 + 2] = fmaf(sv, v4.z, av[og * 4 + 2]);
            av[og * 4 + 3] = fmaf(sv, v4.w, av[og * 4 + 3]);
        }
    }
    uint_t kp[16];
    #pragma unroll
    for (int o = 0; o < 16; ++o)
        kp[o] = (uint_t)bf16rne(ak[2 * o] + kb[2 * o])
              | ((uint_t)bf16rne(ak[2 * o + 1] + kb[2 * o + 1]) << 16);
    uint4* kdst = (uint4*)(ktb + (size_t)idx * 32);
    kdst[0] = make_uint4(kp[0], kp[1], kp[2], kp[3]);
    kdst[1] = make_uint4(kp[4], kp[5], kp[6], kp[7]);
    kdst[2] = make_uint4(kp[8], kp[9], kp[10], kp[11]);
    kdst[3] = make_uint4(kp[12], kp[13], kp[14], kp[15]);
    #pragma unroll
    for (int o = 0; o < 32; ++o)
        vtb[((size_t)bh * 32 + o) * NPOS + pos] = bf16rne(av[o] + vb[o]);
}

// ---------------------------------------------------------------------------
// 7. MFMA flash attention. grid (13 qtile, 32 bh), 256 thr = 4 waves.
//    Q-frags direct from global bf16 [b][s][256]; no barriers at all.
//    Output: attnT packed-split u32 [b][s][256] for streaming o-proj.
__global__ __launch_bounds__(256) void k_attn_mfma(const ushort_t* __restrict__ qbf,
                                                   const ushort_t* __restrict__ ktb,
                                                   const ushort_t* __restrict__ vtb,
                                                   uint_t* __restrict__ attnT) {
    const int qt = blockIdx.x, bh = blockIdx.y;
    const int b = bh >> 3, head = bh & 7;
    const int tid = threadIdx.x, lane = tid & 63, wid = tid >> 6;
    const int n = lane & 15, g = lane >> 4;

    __shared__ __align__(16) ushort_t sP[4][64 * 72];    // per-wave [q][kv], pad 72

    const int q0 = qt * 256;

    // Q B-frags direct from global: lane n = q row, k = dph
    bf16x8 qf[4];
    #pragma unroll
    for (int nf = 0; nf < 4; ++nf) {
        int srow = min(q0 + wid * 64 + nf * 16 + n, NS - 1);
        qf[nf] = *(const bf16x8*)(qbf + ((size_t)b * NS + srow) * 256 + head * 32 + g * 8);
    }

    const ushort_t* kbase = ktb + (size_t)bh * NPOS * 32;
    const ushort_t* vbase = vtb + (size_t)bh * 32 * NPOS;
    ushort_t* myP = sP[wid];

    f32x4 o_acc[2][4];
    #pragma unroll
    for (int i = 0; i < 2; ++i)
        #pragma unroll
        for (int j = 0; j < 4; ++j)
            o_acc[i][j] = (f32x4){0.f, 0.f, 0.f, 0.f};
    float mrun[4] = {-1e30f, -1e30f, -1e30f, -1e30f};
    float lrun[4] = {0.f, 0.f, 0.f, 0.f};

    for (int t = 0; t < 12; ++t) {
        const int kvt = t * 64;
        bf16x8 kf[4];
        #pragma unroll
        for (int mf = 0; mf < 4; ++mf)
            kf[mf] = *(const bf16x8*)(kbase + (size_t)(kvt + mf * 16 + n) * 32 + g * 8);
        bf16x8 vf[2][2];
        #pragma unroll
        for (int mv = 0; mv < 2; ++mv)
            #pragma unroll
            for (int kc = 0; kc < 2; ++kc)
                vf[mv][kc] = *(const bf16x8*)(vbase + (size_t)(mv * 16 + n) * NPOS
                                              + kvt + kc * 32 + g * 8);

        f32x4 acc[4][4];
        #pragma unroll
        for (int mf = 0; mf < 4; ++mf)
            #pragma unroll
            for (int nf = 0; nf < 4; ++nf)
                acc[mf][nf] = __builtin_amdgcn_mfma_f32_16x16x32_bf16(
                    kf[mf], qf[nf], (f32x4){0.f, 0.f, 0.f, 0.f}, 0, 0, 0);

        #pragma unroll
        for (int nf = 0; nf < 4; ++nf) {
            float s[4][4];
            float tmax = -1e30f;
            #pragma unroll
            for (int mf = 0; mf < 4; ++mf)
                #pragma unroll
                for (int r = 0; r < 4; ++r) {
                    s[mf][r] = acc[mf][nf][r] * (1.f / 16.f);
                    tmax = fmaxf(tmax, s[mf][r]);
                }
            tmax = fmaxf(tmax, __shfl_xor(tmax, 16));
            tmax = fmaxf(tmax, __shfl_xor(tmax, 32));
            float mnew = fmaxf(mrun[nf], tmax);
            float corr = __expf(mrun[nf] - mnew);
            mrun[nf] = mnew;
            float psum = 0.f;
            float p[4][4];
            #pragma unroll
            for (int mf = 0; mf < 4; ++mf)
                #pragma unroll
                for (int r = 0; r < 4; ++r) {
                    p[mf][r] = __expf(s[mf][r] - mnew);
                    psum += p[mf][r];
                }
            psum += __shfl_xor(psum, 16);
            psum += __shfl_xor(psum, 32);
            lrun[nf] = lrun[nf] * corr + psum;
            #pragma unroll
            for (int mv = 0; mv < 2; ++mv)
                #pragma unroll
                for (int r = 0; r < 4; ++r)
                    o_acc[mv][nf][r] *= corr;
            #pragma unroll
            for (int mf = 0; mf < 4; ++mf) {
                uint_t lo = cvtpk_bf16(p[mf][0], p[mf][1]);
                uint_t hi = cvtpk_bf16(p[mf][2], p[mf][3]);
                *(uint2*)(myP + (nf * 16 + n) * 72 + mf * 16 + g * 4) =
                    make_uint2(lo, hi);
            }
        }

        #pragma unroll
        for (int kc = 0; kc < 2; ++kc)
            #pragma unroll
            for (int nf = 0; nf < 4; ++nf) {
                bf16x8 pb = *(const bf16x8*)(myP + (nf * 16 + n) * 72
                                             + kc * 32 + g * 8);
                #pragma unroll
                for (int mv = 0; mv < 2; ++mv)
                    o_acc[mv][nf] = __builtin_amdgcn_mfma_f32_16x16x32_bf16(
                        vf[mv][kc], pb, o_acc[mv][nf], 0, 0, 0);
            }
    }

    // epilog tile: kv 768..783
    {
        const int kvt = 768;
        bf16x8 kf0 = *(const bf16x8*)(kbase + (size_t)(kvt + n) * 32 + g * 8);
        bf16x8 vf[2];
        int kvo = kvt + g * 8; if (kvo > 776) kvo = 776;
        #pragma unroll
        for (int mv = 0; mv < 2; ++mv)
            vf[mv] = *(const bf16x8*)(vbase + (size_t)(mv * 16 + n) * NPOS + kvo);

        f32x4 acc0[4];
        #pragma unroll
        for (int nf = 0; nf < 4; ++nf)
            acc0[nf] = __builtin_amdgcn_mfma_f32_16x16x32_bf16(
                kf0, qf[nf], (f32x4){0.f, 0.f, 0.f, 0.f}, 0, 0, 0);

        #pragma unroll
        for (int nf = 0; nf < 4; ++nf) {
            float s[4], tmax = -1e30f;
            #pragma unroll
            for (int r = 0; r < 4; ++r) {
                s[r] = acc0[nf][r] * (1.f / 16.f);
                tmax = fmaxf(tmax, s[r]);
            }
            tmax = fmaxf(tmax, __shfl_xor(tmax, 16));
            tmax = fmaxf(tmax, __shfl_xor(tmax, 32));
            float mnew = fmaxf(mrun[nf], tmax);
            float corr = __expf(mrun[nf] - mnew);
            mrun[nf] = mnew;
            float psum = 0.f, p[4];
            #pragma unroll
            for (int r = 0; r < 4; ++r) { p[r] = __expf(s[r] - mnew); psum += p[r]; }
            psum += __shfl_xor(psum, 16);
            psum += __shfl_xor(psum, 32);
            lrun[nf] = lrun[nf] * corr + psum;
            #pragma unroll
            for (int mv = 0; mv < 2; ++mv)
                #pragma unroll
                for (int r = 0; r < 4; ++r)
                    o_acc[mv][nf][r] *= corr;
            uint_t lo = cvtpk_bf16(p[0], p[1]);
            uint_t hi = cvtpk_bf16(p[2], p[3]);
            *(uint2*)(myP + (nf * 16 + n) * 72 + g * 4) = make_uint2(lo, hi);
            *(uint2*)(myP + (nf * 16 + n) * 72 + 16 + g * 4) = make_uint2(0u, 0u);
        }
        #pragma unroll
        for (int nf = 0; nf < 4; ++nf) {
            bf16x8 pb = *(const bf16x8*)(myP + (nf * 16 + n) * 72 + g * 8);
            #pragma unroll
            for (int mv = 0; mv < 2; ++mv)
                o_acc[mv][nf] = __builtin_amdgcn_mfma_f32_16x16x32_bf16(
                    vf[mv], pb, o_acc[mv][nf], 0, 0, 0);
        }
    }

    // normalize + store attnT packed-split [b][s][256]
    #pragma unroll
    for (int nf = 0; nf < 4; ++nf) {
        float inv = 1.f / lrun[nf];
        int qpos = q0 + wid * 64 + nf * 16 + n;
        if (qpos < NS) {
            #pragma unroll
            for (int mv = 0; mv < 2; ++mv) {
                uint_t pk[4];
                #pragma unroll
                for (int r = 0; r < 4; ++r)
                    pk[r] = packsplit(o_acc[mv][nf][r] * inv);
                *(uint4*)(attnT + ((size_t)b * NS + qpos) * 256
                          + head * 32 + mv * 16 + g * 4) =
                    make_uint4(pk[0], pk[1], pk[2], pk[3]);
            }
        }
    }
}

// ---------------------------------------------------------------------------
extern "C" void kernel_launch(void* const* d_in, const int* in_sizes, int n_in,
                              void* d_out, int out_size, void* d_ws, size_t ws_size,
                              hipStream_t stream) {
    const float* query = (const float*)d_in[0];
    const float* x     = (const float*)d_in[1];
    const float* refp  = (const float*)d_in[2];
    const float* pe    = (const float*)d_in[3];
    const float* w1    = (const float*)d_in[4];
    const float* b1    = (const float*)d_in[5];
    const float* lng   = (const float*)d_in[6];
    const float* lnb   = (const float*)d_in[7];
    const float* w2    = (const float*)d_in[8];
    const float* b2    = (const float*)d_in[9];
    const float* qw    = (const float*)d_in[10];
    const float* qb    = (const float*)d_in[11];
    const float* kw    = (const float*)d_in[12];
    const float* kb    = (const float*)d_in[13];
    const float* vw    = (const float*)d_in[14];
    const float* vb    = (const float*)d_in[15];
    const float* ow    = (const float*)d_in[16];
    const float* ob    = (const float*)d_in[17];

    float* ws  = (float*)d_ws;
    float* out = (float*)d_out;

    uint_t*   rec    = (uint_t*)(ws + OFF_REC);
    float*    hpart  = ws + OFF_HPART;
    float*    loc    = ws + OFF_LOC;
    float*    samp   = ws + OFF_SAMP;
    ushort_t* ktb    = (ushort_t*)(ws + OFF_KTB);
    ushort_t* vtb    = (ushort_t*)(ws + OFF_VTB);
    ushort_t* w256   = (ushort_t*)(ws + OFF_W256);
    ushort_t* wrep_hi = (ushort_t*)(ws + OFF_WREPC);
    uint_t*   qpe    = (uint_t*)(ws + OFF_QPE);     // alias WREPC (dead after conv)
    ushort_t* qbf    = (ushort_t*)(ws + OFF_QBF);   // alias REC (dead after conv)
    uint_t*   attnT  = (uint_t*)(ws + OFF_ATTNT);   // alias HPART (dead after lnoff)

    ushort_t* qwh = w256;
    ushort_t* qwl = w256 + 65536;
    ushort_t* owh = w256 + 131072;
    ushort_t* owl = w256 + 196608;

    k_pool<<<6272, 256, 0, stream>>>(query, x, rec);
    k_wrepack<<<512, 256, 0, stream>>>(w1, wrep_hi, wrep_hi + 3276800u);
    k_wrep256<<<256, 256, 0, stream>>>(qw, ow, w256);
    k_conv_mfma<<<224, 512, 0, stream>>>(rec, wrep_hi, hpart);
    k_lnoff<<<dim3(784, 4), 256, 0, stream>>>(hpart, b1, lng, lnb, w2, b2, refp, loc);
    k_gsample<<<98, 256, 0, stream>>>(x, loc, samp);
    k_qpe<<<dim3(49, 4), 256, 0, stream>>>(query, pe, qpe);
    k_proj<0><<<dim3(25, 2, 4), 256, 0, stream>>>(qpe, qwh, qwl, qb, nullptr, qbf);
    k_kv<<<98, 256, 0, stream>>>(samp, kw, kb, vw, vb, ktb, vtb);
    k_attn_mfma<<<dim3(13, 32), 256, 0, stream>>>(qbf, ktb, vtb, attnT);
    k_proj<1><<<dim3(25, 2, 4), 256, 0, stream>>>(attnT, owh, owl, ob, out, nullptr);
}